// Round 2
// baseline (2862.041 us; speedup 1.0000x reference)
//
#include <hip/hip_runtime.h>
#include <hip/hip_bf16.h>

namespace {
constexpr int kN    = 50000;
constexpr int kE    = 800000;
constexpr int kEtot = kE + kN;   // 850000 (self-loops appended)
constexpr int kEd   = 16;
constexpr int kH    = 8;
constexpr int kD    = 32;
constexpr int kC    = kH * kD;   // 256
constexpr int kNM   = 500;
}

// ---------------- utility ----------------
__global__ void gat_zero32(unsigned int* p, int n) {
  int i = blockIdx.x * blockDim.x + threadIdx.x;
  if (i < n) p[i] = 0u;
}

// ---------------- CSR build (shared by all 3 layers) ----------------
__global__ void gat_count(const int* __restrict__ ei, const float* __restrict__ ea,
                          int* __restrict__ deg, float* __restrict__ ea_loop) {
  int e = blockIdx.x * blockDim.x + threadIdx.x;
  if (e >= kE) return;
  int d = ei[kE + e];
  atomicAdd(&deg[d], 1);
  const float* row = ea + (long)e * kEd;
#pragma unroll
  for (int c = 0; c < kEd; c++) atomicAdd(&ea_loop[d * kEd + c], row[c]);
}

__global__ void gat_scan(const int* __restrict__ deg, int* __restrict__ offs) {
  __shared__ int sums[1024];
  int t = threadIdx.x;
  constexpr int CH = (kN + 1023) / 1024;  // 49
  int lo = t * CH, hi = min(lo + CH, kN);
  int s = 0;
  for (int i = lo; i < hi; i++) s += deg[i] + 1;  // +1 self-loop
  sums[t] = s;
  __syncthreads();
  for (int off = 1; off < 1024; off <<= 1) {
    int v = (t >= off) ? sums[t - off] : 0;
    __syncthreads();
    sums[t] += v;
    __syncthreads();
  }
  int base = sums[t] - s;  // exclusive
  for (int i = lo; i < hi; i++) { offs[i] = base; base += deg[i] + 1; }
  if (t == 1023) offs[kN] = kEtot;
}

__global__ void gat_fill(const int* __restrict__ ei, const int* __restrict__ offs,
                         int* __restrict__ fillc, int* __restrict__ el) {
  int e = blockIdx.x * blockDim.x + threadIdx.x;
  if (e >= kEtot) return;
  int d = (e < kE) ? ei[kE + e] : (e - kE);
  int pos = offs[d] + atomicAdd(&fillc[d], 1);
  el[pos] = e;
}

// ---------------- generic fp32 tiled GEMM: C = act(A @ Bw + bias) ----------------
// amode: 0 = A fp32 (Af), 2 = A is concat[h1,h2,h3,hpool[batch]]
__global__ __launch_bounds__(256) void gat_gemm(
    int M, int K, int Ncols,
    const float* __restrict__ Af, int amode,
    const float* __restrict__ h1, const float* __restrict__ h2, const float* __restrict__ h3,
    const float* __restrict__ hpool, const int* __restrict__ batch,
    const float* __restrict__ Bw, const float* __restrict__ bias,
    float* __restrict__ Cout, int act) {
  __shared__ float As[16][65];
  __shared__ float Bs[16][65];
  int tid = threadIdx.x;
  int rowBase = blockIdx.y * 64;
  int colBase = blockIdx.x * 64;
  int ty = tid >> 4, tx = tid & 15;
  float acc[4][4] = {};
  for (int k0 = 0; k0 < K; k0 += 16) {
    {  // A tile 64x16
      int r = tid >> 2;
      int kk = (tid & 3) * 4;
      int row = rowBase + r;
      if (row < M) {
#pragma unroll
        for (int u = 0; u < 4; u++) {
          int k = k0 + kk + u;
          float v = 0.f;
          if (k < K) {
            if (amode == 0) v = Af[(long)row * K + k];
            else {
              int j = k >> 8, kc = k & 255;
              if (j == 0) v = h1[(long)row * kC + kc];
              else if (j == 1) v = h2[(long)row * kC + kc];
              else if (j == 2) v = h3[(long)row * kC + kc];
              else v = hpool[(long)batch[row] * kC + kc];
            }
          }
          As[kk + u][r] = v;
        }
      } else {
#pragma unroll
        for (int u = 0; u < 4; u++) As[kk + u][r] = 0.f;
      }
    }
    {  // B tile 16x64
      int kr = tid >> 4;
      int c = (tid & 15) * 4;
      int k = k0 + kr;
#pragma unroll
      for (int u = 0; u < 4; u++) {
        int col = colBase + c + u;
        float v = 0.f;
        if (k < K && col < Ncols) v = Bw[(long)k * Ncols + col];
        Bs[kr][c + u] = v;
      }
    }
    __syncthreads();
#pragma unroll
    for (int kk = 0; kk < 16; kk++) {
      float ra[4], rb[4];
#pragma unroll
      for (int i = 0; i < 4; i++) ra[i] = As[kk][ty * 4 + i];
#pragma unroll
      for (int j = 0; j < 4; j++) rb[j] = Bs[kk][tx * 4 + j];
#pragma unroll
      for (int i = 0; i < 4; i++)
#pragma unroll
        for (int j = 0; j < 4; j++) acc[i][j] += ra[i] * rb[j];
    }
    __syncthreads();
  }
#pragma unroll
  for (int i = 0; i < 4; i++) {
    int row = rowBase + ty * 4 + i;
    if (row >= M) continue;
#pragma unroll
    for (int j = 0; j < 4; j++) {
      int col = colBase + tx * 4 + j;
      if (col >= Ncols) continue;
      float v = acc[i][j];
      if (bias) v += bias[col];
      if (act == 1) v = v > 0.f ? v : 0.01f * v;
      Cout[(long)row * Ncols + col] = v;
    }
  }
}

// ---------------- per-layer small kernels ----------------
// Q[c,h] = sum_d We[c, h*32+d] * ae[h,d]
__global__ void gat_make_q(const float* __restrict__ We,
                           const float* __restrict__ ae, float* __restrict__ Q) {
  int t = threadIdx.x;
  if (t >= kEd * kH) return;
  int c = t >> 3, h = t & 7;
  float s = 0.f;
#pragma unroll
  for (int d = 0; d < kD; d++) s += We[c * kC + h * kD + d] * ae[h * kD + d];
  Q[c * kH + h] = s;
}

// a_src[n,h] = xl[n,h,:].a_s[h,:] ; a_dst likewise
__global__ void gat_node_coef(const float* __restrict__ xl, const float* __restrict__ as_,
                              const float* __restrict__ ad_, float* __restrict__ a_src,
                              float* __restrict__ a_dst) {
  int t = blockIdx.x * blockDim.x + threadIdx.x;
  if (t >= kN * kH) return;
  int n = t >> 3, h = t & 7;
  const float* row = xl + (long)n * kC + h * kD;
  float ss = 0.f, sd = 0.f;
#pragma unroll
  for (int d = 0; d < kD; d++) {
    float v = row[d];
    ss += v * as_[h * kD + d];
    sd += v * ad_[h * kD + d];
  }
  a_src[t] = ss;
  a_dst[t] = sd;
}

// alpha[e,h] = leakyrelu_0.2( a_src[src] + a_dst[dst] + ea_row . Q[:,h] )
__global__ void gat_edge_alpha(const int* __restrict__ ei, const float* __restrict__ ea,
                               const float* __restrict__ ea_loop, const float* __restrict__ Q,
                               const float* __restrict__ a_src, const float* __restrict__ a_dst,
                               float* __restrict__ alpha) {
  int e = blockIdx.x * blockDim.x + threadIdx.x;
  if (e >= kEtot) return;
  int s, d;
  float eav[kEd];
  if (e < kE) {
    s = ei[e];
    d = ei[kE + e];
    const float4* r = (const float4*)(ea + (long)e * kEd);
#pragma unroll
    for (int q = 0; q < kEd / 4; q++) {
      float4 v = r[q];
      eav[q * 4 + 0] = v.x; eav[q * 4 + 1] = v.y;
      eav[q * 4 + 2] = v.z; eav[q * 4 + 3] = v.w;
    }
  } else {
    s = d = e - kE;
    const float* r = ea_loop + (long)s * kEd;
#pragma unroll
    for (int c = 0; c < kEd; c++) eav[c] = r[c];
  }
  const float* asr = a_src + s * kH;
  const float* adr = a_dst + d * kH;
#pragma unroll
  for (int h = 0; h < kH; h++) {
    float q = 0.f;
#pragma unroll
    for (int c = 0; c < kEd; c++) q += eav[c] * Q[c * kH + h];
    float a = asr[h] + adr[h] + q;
    a = a > 0.f ? a : 0.2f * a;
    alpha[(long)e * kH + h] = a;
  }
}

// per (node, head): segment softmax in place (alpha -> att)
__global__ void gat_softmax(const int* __restrict__ offs, const int* __restrict__ el,
                            float* __restrict__ alpha) {
  int t = blockIdx.x * blockDim.x + threadIdx.x;
  if (t >= kN * kH) return;
  int n = t >> 3, h = t & 7;
  int lo = offs[n], hi = offs[n + 1];
  float m = -1e30f;
  for (int j = lo; j < hi; j++) m = fmaxf(m, alpha[(long)el[j] * kH + h]);
  float s = 0.f;
  for (int j = lo; j < hi; j++) s += __expf(alpha[(long)el[j] * kH + h] - m);
  float inv = 1.f / s;
  for (int j = lo; j < hi; j++) {
    long idx = (long)el[j] * kH + h;
    alpha[idx] = __expf(alpha[idx] - m) * inv;
  }
}

// one wave per node: out[n,c] = sum_e att[e, c/32] * xl[src_e, c]  + b[c]
__global__ __launch_bounds__(256) void gat_aggregate(
    const int* __restrict__ offs, const int* __restrict__ el, const int* __restrict__ ei,
    const float* __restrict__ alpha, const float* __restrict__ xl,
    const float* __restrict__ bias, float* __restrict__ out) {
  int n = blockIdx.x * 4 + (threadIdx.x >> 6);
  if (n >= kN) return;
  int lane = threadIdx.x & 63;
  int c = lane * 4;
  int h = lane >> 3;
  int lo = offs[n], hi = offs[n + 1];
  float a0 = 0.f, a1 = 0.f, a2 = 0.f, a3 = 0.f;
  for (int j = lo; j < hi; j++) {
    int e = el[j];
    int s = (e < kE) ? ei[e] : (e - kE);
    float att = alpha[(long)e * kH + h];
    float4 v = *(const float4*)(xl + (long)s * kC + c);
    a0 += att * v.x; a1 += att * v.y; a2 += att * v.z; a3 += att * v.w;
  }
  float4 o;
  o.x = a0 + bias[c];
  o.y = a1 + bias[c + 1];
  o.z = a2 + bias[c + 2];
  o.w = a3 + bias[c + 3];
  *(float4*)(out + (long)n * kC + c) = o;
}

// ---------------- pooling + final MLP ----------------
__global__ void gat_pool(const float* __restrict__ h3, const int* __restrict__ batch,
                         float* __restrict__ hpool) {
  int t = blockIdx.x * blockDim.x + threadIdx.x;
  if (t >= kN * 64) return;
  int n = t >> 6, i = (t & 63) * 4;
  int m = batch[n];
  const float* r = h3 + (long)n * kC + i;
  float* p = hpool + (long)m * kC + i;
  atomicAdd(&p[0], r[0]);
  atomicAdd(&p[1], r[1]);
  atomicAdd(&p[2], r[2]);
  atomicAdd(&p[3], r[3]);
}

__global__ void gat_mlp3(const float* __restrict__ c2, const float* __restrict__ lw3,
                         const float* __restrict__ lb3, float* __restrict__ out) {
  int n = blockIdx.x * blockDim.x + threadIdx.x;
  if (n >= kN) return;
  float s = lb3[0];
  const float* r = c2 + (long)n * 64;
#pragma unroll
  for (int k = 0; k < 64; k++) s += r[k] * lw3[k];
  float v = 1.f / (1.f + __expf(-s));
  out[n] = v;
}

// ---------------- host ----------------
static inline int cdiv(int a, int b) { return (a + b - 1) / b; }

extern "C" void kernel_launch(void* const* d_in, const int* in_sizes, int n_in,
                              void* d_out, int out_size, void* d_ws, size_t ws_size,
                              hipStream_t stream) {
  (void)in_sizes; (void)n_in; (void)out_size; (void)ws_size;
  const float* x = (const float*)d_in[0];
  const int* ei = (const int*)d_in[1];
  const float* ea = (const float*)d_in[2];
  const int* batch = (const int*)d_in[3];
  const float *W[3], *as_[3], *ad_[3], *We_[3], *ae_[3], *bb[3];
  for (int l = 0; l < 3; l++) {
    W[l]   = (const float*)d_in[4 + 6 * l];
    as_[l] = (const float*)d_in[5 + 6 * l];
    ad_[l] = (const float*)d_in[6 + 6 * l];
    We_[l] = (const float*)d_in[7 + 6 * l];
    ae_[l] = (const float*)d_in[8 + 6 * l];
    bb[l]  = (const float*)d_in[9 + 6 * l];
  }
  const float* lw1 = (const float*)d_in[22];
  const float* lb1 = (const float*)d_in[23];
  const float* lw2 = (const float*)d_in[24];
  const float* lb2 = (const float*)d_in[25];
  const float* lw3 = (const float*)d_in[26];
  const float* lb3 = (const float*)d_in[27];
  float* out = (float*)d_out;

  char* p = (char*)d_ws;
  auto carve = [&](size_t bytes) -> void* {
    void* r = (void*)p;
    p += (bytes + 255) & ~(size_t)255;
    return r;
  };
  float* h1      = (float*)carve(sizeof(float) * (size_t)kN * kC);
  float* h2      = (float*)carve(sizeof(float) * (size_t)kN * kC);
  float* h3      = (float*)carve(sizeof(float) * (size_t)kN * kC);
  float* xl      = (float*)carve(sizeof(float) * (size_t)kN * kC);
  float* alpha   = (float*)carve(sizeof(float) * (size_t)kEtot * kH);
  float* a_src   = (float*)carve(sizeof(float) * (size_t)kN * kH);
  float* a_dst   = (float*)carve(sizeof(float) * (size_t)kN * kH);
  float* ea_loop = (float*)carve(sizeof(float) * (size_t)kN * kEd);
  float* Q       = (float*)carve(sizeof(float) * 128);
  float* hpool   = (float*)carve(sizeof(float) * (size_t)kNM * kC);
  int* deg   = (int*)carve(sizeof(int) * kN);
  int* fillc = (int*)carve(sizeof(int) * kN);
  int* offs  = (int*)carve(sizeof(int) * (kN + 1));
  int* el    = (int*)carve(sizeof(int) * kEtot);
  // dead-buffer aliases for MLP intermediates
  float* c1 = alpha;  // N*96  <= Etot*8
  float* c2 = xl;     // N*64  <= N*256

  // ---- zero accumulators ----
  gat_zero32<<<cdiv(kN, 256), 256, 0, stream>>>((unsigned int*)deg, kN);
  gat_zero32<<<cdiv(kN, 256), 256, 0, stream>>>((unsigned int*)fillc, kN);
  gat_zero32<<<cdiv(kN * kEd, 256), 256, 0, stream>>>((unsigned int*)ea_loop, kN * kEd);
  gat_zero32<<<cdiv(kNM * kC, 256), 256, 0, stream>>>((unsigned int*)hpool, kNM * kC);

  // ---- CSR build + self-loop edge_attr ----
  gat_count<<<cdiv(kE, 256), 256, 0, stream>>>(ei, ea, deg, ea_loop);
  gat_scan<<<1, 1024, 0, stream>>>(deg, offs);
  gat_fill<<<cdiv(kEtot, 256), 256, 0, stream>>>(ei, offs, fillc, el);

  // ---- 3 GAT layers ----
  const float* hin[3] = {x, h1, h2};
  float* hout[3] = {h1, h2, h3};
  int kdim[3] = {64, kC, kC};
  for (int l = 0; l < 3; l++) {
    dim3 ggrid(kC / 64, cdiv(kN, 64));
    gat_gemm<<<ggrid, 256, 0, stream>>>(kN, kdim[l], kC,
                                        hin[l], 0,
                                        nullptr, nullptr, nullptr, nullptr, nullptr,
                                        W[l], nullptr, xl, 0);
    gat_make_q<<<1, 128, 0, stream>>>(We_[l], ae_[l], Q);
    gat_node_coef<<<cdiv(kN * kH, 256), 256, 0, stream>>>(xl, as_[l], ad_[l], a_src, a_dst);
    gat_edge_alpha<<<cdiv(kEtot, 256), 256, 0, stream>>>(ei, ea, ea_loop, Q, a_src, a_dst, alpha);
    gat_softmax<<<cdiv(kN * kH, 256), 256, 0, stream>>>(offs, el, alpha);
    gat_aggregate<<<cdiv(kN, 4), 256, 0, stream>>>(offs, el, ei, alpha, xl, bb[l], hout[l]);
  }

  // ---- pooling ----
  gat_pool<<<cdiv(kN * 64, 256), 256, 0, stream>>>(h3, batch, hpool);

  // ---- MLP ----
  {
    dim3 g1(cdiv(96, 64), cdiv(kN, 64));
    gat_gemm<<<g1, 256, 0, stream>>>(kN, 4 * kC, 96, nullptr, 2,
                                     h1, h2, h3, hpool, batch, lw1, lb1, c1, 1);
    dim3 g2(1, cdiv(kN, 64));
    gat_gemm<<<g2, 256, 0, stream>>>(kN, 96, 64, c1, 0,
                                     nullptr, nullptr, nullptr, nullptr, nullptr,
                                     lw2, lb2, c2, 1);
    gat_mlp3<<<cdiv(kN, 256), 256, 0, stream>>>(c2, lw3, lb3, out);
  }
}

// Round 3
// 2112.369 us; speedup vs baseline: 1.3549x; 1.3549x over previous
//
#include <hip/hip_runtime.h>
#include <hip/hip_bf16.h>

namespace {
constexpr int kN    = 50000;
constexpr int kE    = 800000;
constexpr int kEtot = kE + kN;   // 850000 (self-loops appended)
constexpr int kEd   = 16;
constexpr int kH    = 8;
constexpr int kD    = 32;
constexpr int kC    = kH * kD;   // 256
constexpr int kNM   = 500;
}

// ---------------- utility ----------------
__global__ void gat_zero32(unsigned int* p, int n) {
  int i = blockIdx.x * blockDim.x + threadIdx.x;
  if (i < n) p[i] = 0u;
}

// ---------------- CSR build (shared by all 3 layers) ----------------
__global__ void gat_count(const int* __restrict__ ei, int* __restrict__ deg) {
  int e = blockIdx.x * blockDim.x + threadIdx.x;
  if (e >= kE) return;
  atomicAdd(&deg[ei[kE + e]], 1);
}

__global__ void gat_scan(const int* __restrict__ deg, int* __restrict__ offs) {
  __shared__ int sums[1024];
  int t = threadIdx.x;
  constexpr int CH = (kN + 1023) / 1024;  // 49
  int lo = t * CH, hi = min(lo + CH, kN);
  int s = 0;
  for (int i = lo; i < hi; i++) s += deg[i] + 1;  // +1 self-loop
  sums[t] = s;
  __syncthreads();
  for (int off = 1; off < 1024; off <<= 1) {
    int v = (t >= off) ? sums[t - off] : 0;
    __syncthreads();
    sums[t] += v;
    __syncthreads();
  }
  int base = sums[t] - s;  // exclusive
  for (int i = lo; i < hi; i++) { offs[i] = base; base += deg[i] + 1; }
  if (t == 1023) offs[kN] = kEtot;
}

__global__ void gat_fill(const int* __restrict__ ei, const int* __restrict__ offs,
                         int* __restrict__ fillc, int* __restrict__ el) {
  int e = blockIdx.x * blockDim.x + threadIdx.x;
  if (e >= kEtot) return;
  int d = (e < kE) ? ei[kE + e] : (e - kE);
  int pos = offs[d] + atomicAdd(&fillc[d], 1);
  el[pos] = e;
}

// ea_loop[n,c] = sum over real in-edges e of ea[e,c]   (atomic-free CSR walk)
__global__ void gat_ealoop(const int* __restrict__ offs, const int* __restrict__ el,
                           const float* __restrict__ ea, float* __restrict__ ea_loop) {
  int t = blockIdx.x * blockDim.x + threadIdx.x;
  if (t >= kN * kEd) return;
  int n = t >> 4, c = t & 15;
  int lo = offs[n], hi = offs[n + 1];
  float s = 0.f;
  for (int j = lo; j < hi; j++) {
    int e = el[j];
    if (e < kE) s += ea[(long)e * kEd + c];
  }
  ea_loop[t] = s;
}

// ---------------- generic fp32 tiled GEMM: C = act(A @ Bw + bias) ----------------
// amode: 0 = A fp32 (Af), 2 = A is concat[h1,h2,h3,hpool[batch]]
__global__ __launch_bounds__(256) void gat_gemm(
    int M, int K, int Ncols,
    const float* __restrict__ Af, int amode,
    const float* __restrict__ h1, const float* __restrict__ h2, const float* __restrict__ h3,
    const float* __restrict__ hpool, const int* __restrict__ batch,
    const float* __restrict__ Bw, const float* __restrict__ bias,
    float* __restrict__ Cout, int act) {
  __shared__ float As[16][65];
  __shared__ float Bs[16][65];
  int tid = threadIdx.x;
  int rowBase = blockIdx.y * 64;
  int colBase = blockIdx.x * 64;
  int ty = tid >> 4, tx = tid & 15;
  float acc[4][4] = {};
  for (int k0 = 0; k0 < K; k0 += 16) {
    {  // A tile 64x16
      int r = tid >> 2;
      int kk = (tid & 3) * 4;
      int row = rowBase + r;
      if (row < M) {
#pragma unroll
        for (int u = 0; u < 4; u++) {
          int k = k0 + kk + u;
          float v = 0.f;
          if (k < K) {
            if (amode == 0) v = Af[(long)row * K + k];
            else {
              int j = k >> 8, kc = k & 255;
              if (j == 0) v = h1[(long)row * kC + kc];
              else if (j == 1) v = h2[(long)row * kC + kc];
              else if (j == 2) v = h3[(long)row * kC + kc];
              else v = hpool[(long)batch[row] * kC + kc];
            }
          }
          As[kk + u][r] = v;
        }
      } else {
#pragma unroll
        for (int u = 0; u < 4; u++) As[kk + u][r] = 0.f;
      }
    }
    {  // B tile 16x64
      int kr = tid >> 4;
      int c = (tid & 15) * 4;
      int k = k0 + kr;
#pragma unroll
      for (int u = 0; u < 4; u++) {
        int col = colBase + c + u;
        float v = 0.f;
        if (k < K && col < Ncols) v = Bw[(long)k * Ncols + col];
        Bs[kr][c + u] = v;
      }
    }
    __syncthreads();
#pragma unroll
    for (int kk = 0; kk < 16; kk++) {
      float ra[4], rb[4];
#pragma unroll
      for (int i = 0; i < 4; i++) ra[i] = As[kk][ty * 4 + i];
#pragma unroll
      for (int j = 0; j < 4; j++) rb[j] = Bs[kk][tx * 4 + j];
#pragma unroll
      for (int i = 0; i < 4; i++)
#pragma unroll
        for (int j = 0; j < 4; j++) acc[i][j] += ra[i] * rb[j];
    }
    __syncthreads();
  }
#pragma unroll
  for (int i = 0; i < 4; i++) {
    int row = rowBase + ty * 4 + i;
    if (row >= M) continue;
#pragma unroll
    for (int j = 0; j < 4; j++) {
      int col = colBase + tx * 4 + j;
      if (col >= Ncols) continue;
      float v = acc[i][j];
      if (bias) v += bias[col];
      if (act == 1) v = v > 0.f ? v : 0.01f * v;
      Cout[(long)row * Ncols + col] = v;
    }
  }
}

// ---------------- per-layer small kernels ----------------
// Q[c,h] = sum_d We[c, h*32+d] * ae[h,d]
__global__ void gat_make_q(const float* __restrict__ We,
                           const float* __restrict__ ae, float* __restrict__ Q) {
  int t = threadIdx.x;
  if (t >= kEd * kH) return;
  int c = t >> 3, h = t & 7;
  float s = 0.f;
#pragma unroll
  for (int d = 0; d < kD; d++) s += We[c * kC + h * kD + d] * ae[h * kD + d];
  Q[c * kH + h] = s;
}

// a_src[n,h] = xl[n,h,:].a_s[h,:] ; a_dst likewise
__global__ void gat_node_coef(const float* __restrict__ xl, const float* __restrict__ as_,
                              const float* __restrict__ ad_, float* __restrict__ a_src,
                              float* __restrict__ a_dst) {
  int t = blockIdx.x * blockDim.x + threadIdx.x;
  if (t >= kN * kH) return;
  int n = t >> 3, h = t & 7;
  const float* row = xl + (long)n * kC + h * kD;
  float ss = 0.f, sd = 0.f;
#pragma unroll
  for (int d = 0; d < kD; d++) {
    float v = row[d];
    ss += v * as_[h * kD + d];
    sd += v * ad_[h * kD + d];
  }
  a_src[t] = ss;
  a_dst[t] = sd;
}

// alpha[e,h] = leakyrelu_0.2( a_src[src] + a_dst[dst] + ea_row . Q[:,h] )
__global__ void gat_edge_alpha(const int* __restrict__ ei, const float* __restrict__ ea,
                               const float* __restrict__ ea_loop, const float* __restrict__ Q,
                               const float* __restrict__ a_src, const float* __restrict__ a_dst,
                               float* __restrict__ alpha) {
  int e = blockIdx.x * blockDim.x + threadIdx.x;
  if (e >= kEtot) return;
  int s, d;
  float eav[kEd];
  if (e < kE) {
    s = ei[e];
    d = ei[kE + e];
    const float4* r = (const float4*)(ea + (long)e * kEd);
#pragma unroll
    for (int q = 0; q < kEd / 4; q++) {
      float4 v = r[q];
      eav[q * 4 + 0] = v.x; eav[q * 4 + 1] = v.y;
      eav[q * 4 + 2] = v.z; eav[q * 4 + 3] = v.w;
    }
  } else {
    s = d = e - kE;
    const float* r = ea_loop + (long)s * kEd;
#pragma unroll
    for (int c = 0; c < kEd; c++) eav[c] = r[c];
  }
  const float* asr = a_src + s * kH;
  const float* adr = a_dst + d * kH;
#pragma unroll
  for (int h = 0; h < kH; h++) {
    float q = 0.f;
#pragma unroll
    for (int c = 0; c < kEd; c++) q += eav[c] * Q[c * kH + h];
    float a = asr[h] + adr[h] + q;
    a = a > 0.f ? a : 0.2f * a;
    alpha[(long)e * kH + h] = a;
  }
}

// per (node, head): segment softmax in place (alpha -> att)
__global__ void gat_softmax(const int* __restrict__ offs, const int* __restrict__ el,
                            float* __restrict__ alpha) {
  int t = blockIdx.x * blockDim.x + threadIdx.x;
  if (t >= kN * kH) return;
  int n = t >> 3, h = t & 7;
  int lo = offs[n], hi = offs[n + 1];
  float m = -1e30f;
  for (int j = lo; j < hi; j++) m = fmaxf(m, alpha[(long)el[j] * kH + h]);
  float s = 0.f;
  for (int j = lo; j < hi; j++) s += __expf(alpha[(long)el[j] * kH + h] - m);
  float inv = 1.f / s;
  for (int j = lo; j < hi; j++) {
    long idx = (long)el[j] * kH + h;
    alpha[idx] = __expf(alpha[idx] - m) * inv;
  }
}

// one wave per node: out[n,c] = sum_e att[e, c/32] * xl[src_e, c]  + b[c]
__global__ __launch_bounds__(256) void gat_aggregate(
    const int* __restrict__ offs, const int* __restrict__ el, const int* __restrict__ ei,
    const float* __restrict__ alpha, const float* __restrict__ xl,
    const float* __restrict__ bias, float* __restrict__ out) {
  int n = blockIdx.x * 4 + (threadIdx.x >> 6);
  if (n >= kN) return;
  int lane = threadIdx.x & 63;
  int c = lane * 4;
  int h = lane >> 3;
  int lo = offs[n], hi = offs[n + 1];
  float a0 = 0.f, a1 = 0.f, a2 = 0.f, a3 = 0.f;
  for (int j = lo; j < hi; j++) {
    int e = el[j];
    int s = (e < kE) ? ei[e] : (e - kE);
    float att = alpha[(long)e * kH + h];
    float4 v = *(const float4*)(xl + (long)s * kC + c);
    a0 += att * v.x; a1 += att * v.y; a2 += att * v.z; a3 += att * v.w;
  }
  float4 o;
  o.x = a0 + bias[c];
  o.y = a1 + bias[c + 1];
  o.z = a2 + bias[c + 2];
  o.w = a3 + bias[c + 3];
  *(float4*)(out + (long)n * kC + c) = o;
}

// ---------------- pooling (batch is sorted -> segmented reduce, no atomics) ----------------
__global__ __launch_bounds__(256) void gat_pool_seg(const float* __restrict__ h3,
                                                    const int* __restrict__ batch,
                                                    float* __restrict__ hpool) {
  int m = blockIdx.x;
  int c = threadIdx.x;
  // binary search: first n with batch[n] >= m, first n with batch[n] >= m+1
  int lo = 0, hi = kN;
  while (lo < hi) { int mid = (lo + hi) >> 1; if (batch[mid] < m) lo = mid + 1; else hi = mid; }
  int start = lo;
  hi = kN;
  while (lo < hi) { int mid = (lo + hi) >> 1; if (batch[mid] < m + 1) lo = mid + 1; else hi = mid; }
  int end = lo;
  float s = 0.f;
  for (int n = start; n < end; n++) s += h3[(long)n * kC + c];
  hpool[(long)m * kC + c] = s;
}

__global__ void gat_mlp3(const float* __restrict__ c2, const float* __restrict__ lw3,
                         const float* __restrict__ lb3, float* __restrict__ out) {
  int n = blockIdx.x * blockDim.x + threadIdx.x;
  if (n >= kN) return;
  float s = lb3[0];
  const float* r = c2 + (long)n * 64;
#pragma unroll
  for (int k = 0; k < 64; k++) s += r[k] * lw3[k];
  float v = 1.f / (1.f + __expf(-s));
  out[n] = v;
}

// ---------------- host ----------------
static inline int cdiv(int a, int b) { return (a + b - 1) / b; }

extern "C" void kernel_launch(void* const* d_in, const int* in_sizes, int n_in,
                              void* d_out, int out_size, void* d_ws, size_t ws_size,
                              hipStream_t stream) {
  (void)in_sizes; (void)n_in; (void)out_size; (void)ws_size;
  const float* x = (const float*)d_in[0];
  const int* ei = (const int*)d_in[1];
  const float* ea = (const float*)d_in[2];
  const int* batch = (const int*)d_in[3];
  const float *W[3], *as_[3], *ad_[3], *We_[3], *ae_[3], *bb[3];
  for (int l = 0; l < 3; l++) {
    W[l]   = (const float*)d_in[4 + 6 * l];
    as_[l] = (const float*)d_in[5 + 6 * l];
    ad_[l] = (const float*)d_in[6 + 6 * l];
    We_[l] = (const float*)d_in[7 + 6 * l];
    ae_[l] = (const float*)d_in[8 + 6 * l];
    bb[l]  = (const float*)d_in[9 + 6 * l];
  }
  const float* lw1 = (const float*)d_in[22];
  const float* lb1 = (const float*)d_in[23];
  const float* lw2 = (const float*)d_in[24];
  const float* lb2 = (const float*)d_in[25];
  const float* lw3 = (const float*)d_in[26];
  const float* lb3 = (const float*)d_in[27];
  float* out = (float*)d_out;

  char* p = (char*)d_ws;
  auto carve = [&](size_t bytes) -> void* {
    void* r = (void*)p;
    p += (bytes + 255) & ~(size_t)255;
    return r;
  };
  float* h1      = (float*)carve(sizeof(float) * (size_t)kN * kC);
  float* h2      = (float*)carve(sizeof(float) * (size_t)kN * kC);
  float* h3      = (float*)carve(sizeof(float) * (size_t)kN * kC);
  float* xl      = (float*)carve(sizeof(float) * (size_t)kN * kC);
  float* alpha   = (float*)carve(sizeof(float) * (size_t)kEtot * kH);
  float* a_src   = (float*)carve(sizeof(float) * (size_t)kN * kH);
  float* a_dst   = (float*)carve(sizeof(float) * (size_t)kN * kH);
  float* ea_loop = (float*)carve(sizeof(float) * (size_t)kN * kEd);
  float* Q       = (float*)carve(sizeof(float) * 128);
  float* hpool   = (float*)carve(sizeof(float) * (size_t)kNM * kC);
  int* deg   = (int*)carve(sizeof(int) * kN);
  int* fillc = (int*)carve(sizeof(int) * kN);
  int* offs  = (int*)carve(sizeof(int) * (kN + 1));
  int* el    = (int*)carve(sizeof(int) * kEtot);
  // dead-buffer aliases for MLP intermediates
  float* c1 = alpha;  // N*96  <= Etot*8
  float* c2 = xl;     // N*64  <= N*256

  // ---- zero counters ----
  gat_zero32<<<cdiv(kN, 256), 256, 0, stream>>>((unsigned int*)deg, kN);
  gat_zero32<<<cdiv(kN, 256), 256, 0, stream>>>((unsigned int*)fillc, kN);

  // ---- CSR build + self-loop edge_attr (atomic-free) ----
  gat_count<<<cdiv(kE, 256), 256, 0, stream>>>(ei, deg);
  gat_scan<<<1, 1024, 0, stream>>>(deg, offs);
  gat_fill<<<cdiv(kEtot, 256), 256, 0, stream>>>(ei, offs, fillc, el);
  gat_ealoop<<<cdiv(kN * kEd, 256), 256, 0, stream>>>(offs, el, ea, ea_loop);

  // ---- 3 GAT layers ----
  const float* hin[3] = {x, h1, h2};
  float* hout[3] = {h1, h2, h3};
  int kdim[3] = {64, kC, kC};
  for (int l = 0; l < 3; l++) {
    dim3 ggrid(kC / 64, cdiv(kN, 64));
    gat_gemm<<<ggrid, 256, 0, stream>>>(kN, kdim[l], kC,
                                        hin[l], 0,
                                        nullptr, nullptr, nullptr, nullptr, nullptr,
                                        W[l], nullptr, xl, 0);
    gat_make_q<<<1, 128, 0, stream>>>(We_[l], ae_[l], Q);
    gat_node_coef<<<cdiv(kN * kH, 256), 256, 0, stream>>>(xl, as_[l], ad_[l], a_src, a_dst);
    gat_edge_alpha<<<cdiv(kEtot, 256), 256, 0, stream>>>(ei, ea, ea_loop, Q, a_src, a_dst, alpha);
    gat_softmax<<<cdiv(kN * kH, 256), 256, 0, stream>>>(offs, el, alpha);
    gat_aggregate<<<cdiv(kN, 4), 256, 0, stream>>>(offs, el, ei, alpha, xl, bb[l], hout[l]);
  }

  // ---- pooling (segmented, batch sorted) ----
  gat_pool_seg<<<kNM, kC, 0, stream>>>(h3, batch, hpool);

  // ---- MLP ----
  {
    dim3 g1(cdiv(96, 64), cdiv(kN, 64));
    gat_gemm<<<g1, 256, 0, stream>>>(kN, 4 * kC, 96, nullptr, 2,
                                     h1, h2, h3, hpool, batch, lw1, lb1, c1, 1);
    dim3 g2(1, cdiv(kN, 64));
    gat_gemm<<<g2, 256, 0, stream>>>(kN, 96, 64, c1, 0,
                                     nullptr, nullptr, nullptr, nullptr, nullptr,
                                     lw2, lb2, c2, 1);
    gat_mlp3<<<cdiv(kN, 256), 256, 0, stream>>>(c2, lw3, lb3, out);
  }
}

// Round 4
// 1396.061 us; speedup vs baseline: 2.0501x; 1.5131x over previous
//
#include <hip/hip_runtime.h>
#include <hip/hip_bf16.h>

namespace {
constexpr int kN    = 50000;
constexpr int kE    = 800000;
constexpr int kEtot = kE + kN;   // 850000 (self-loops appended)
constexpr int kEd   = 16;
constexpr int kH    = 8;
constexpr int kD    = 32;
constexpr int kC    = kH * kD;   // 256
constexpr int kNM   = 500;
}

typedef __attribute__((ext_vector_type(8))) short short8;
typedef __attribute__((ext_vector_type(4))) float floatx4;

__device__ __forceinline__ float b2f(ushort u) {
  union { unsigned u; float f; } v;
  v.u = ((unsigned)u) << 16;
  return v.f;
}
__device__ __forceinline__ ushort f2b(float f) {
  union { float f; unsigned u; } v;
  v.f = f;
  unsigned r = v.u + 0x7fffu + ((v.u >> 16) & 1u);  // RNE
  return (ushort)(r >> 16);
}

// ---------------- utility ----------------
__global__ void gat_zero32(unsigned int* p, int n) {
  int i = blockIdx.x * blockDim.x + threadIdx.x;
  if (i < n) p[i] = 0u;
}

// fp32 -> bf16 flat convert
__global__ void cvt_f2b(const float* __restrict__ in, ushort* __restrict__ out, int n) {
  int i = blockIdx.x * blockDim.x + threadIdx.x;
  if (i < n) out[i] = f2b(in[i]);
}

// Wt[n][k] = bf16(W[k][n]);  W is K x N fp32
__global__ void cvt_wt(const float* __restrict__ W, ushort* __restrict__ Wt, int K, int N) {
  int i = blockIdx.x * blockDim.x + threadIdx.x;
  if (i >= K * N) return;
  int n = i / K, k = i - n * K;
  Wt[i] = f2b(W[(long)k * N + n]);
}

// ---------------- CSR build (shared by all 3 layers) ----------------
__global__ void gat_count(const int* __restrict__ ei, int* __restrict__ deg) {
  int e = blockIdx.x * blockDim.x + threadIdx.x;
  if (e >= kE) return;
  atomicAdd(&deg[ei[kE + e]], 1);
}

__global__ void gat_scan(const int* __restrict__ deg, int* __restrict__ offs) {
  __shared__ int sums[1024];
  int t = threadIdx.x;
  constexpr int CH = (kN + 1023) / 1024;  // 49
  int lo = t * CH, hi = min(lo + CH, kN);
  int s = 0;
  for (int i = lo; i < hi; i++) s += deg[i] + 1;  // +1 self-loop
  sums[t] = s;
  __syncthreads();
  for (int off = 1; off < 1024; off <<= 1) {
    int v = (t >= off) ? sums[t - off] : 0;
    __syncthreads();
    sums[t] += v;
    __syncthreads();
  }
  int base = sums[t] - s;  // exclusive
  for (int i = lo; i < hi; i++) { offs[i] = base; base += deg[i] + 1; }
  if (t == 1023) offs[kN] = kEtot;
}

__global__ void gat_fill(const int* __restrict__ ei, const int* __restrict__ offs,
                         int* __restrict__ fillc, int* __restrict__ el) {
  int e = blockIdx.x * blockDim.x + threadIdx.x;
  if (e >= kEtot) return;
  int d = (e < kE) ? ei[kE + e] : (e - kE);
  int pos = offs[d] + atomicAdd(&fillc[d], 1);
  el[pos] = e;
}

// ea_loop[n,c] = sum over real in-edges e of ea[e,c]   (atomic-free CSR walk)
__global__ void gat_ealoop(const int* __restrict__ offs, const int* __restrict__ el,
                           const float* __restrict__ ea, float* __restrict__ ea_loop) {
  int t = blockIdx.x * blockDim.x + threadIdx.x;
  if (t >= kN * kEd) return;
  int n = t >> 4, c = t & 15;
  int lo = offs[n], hi = offs[n + 1];
  float s = 0.f;
  for (int j = lo; j < hi; j++) {
    int e = el[j];
    if (e < kE) s += ea[(long)e * kEd + c];
  }
  ea_loop[t] = s;
}

// ---------------- bf16 MFMA GEMM ----------------
// C(MxN,fp32) = act( A(MxK,bf16 row-major) @ B + bias )
// B passed pre-transposed: Bt[N][K] bf16.
// AMODE 0: A = A0.  AMODE 2: A row r, col k: j=k>>8 -> {A0,A1,A2,A3[batch[r]]}, each [.][256].
// Block: 256 thr = 4 waves; tile 64(M) x 32(N); BK=64. Wave w: rows w*16..+15, both 16-col tiles.
// LDS k-major blocked: As[kq][row][8], Bs[kq][n][8]  (kq = 8-elem k-chunk) ->
//   frag reads are contiguous 256B per 16-lane phase (conflict-free ds_read_b128).
template <int AMODE>
__global__ __launch_bounds__(256) void gat_gemm_mfma(
    int M, int K, int N,
    const ushort* __restrict__ A0, const ushort* __restrict__ A1,
    const ushort* __restrict__ A2, const ushort* __restrict__ A3,
    const int* __restrict__ batch,
    const ushort* __restrict__ Bt, const float* __restrict__ bias,
    float* __restrict__ C, int act) {
  __shared__ ushort As[8][64][8];  // 8 KB
  __shared__ ushort Bs[8][32][8];  // 4 KB
  int t = threadIdx.x;
  int rowBase = blockIdx.y * 64;
  int colBase = blockIdx.x * 32;
  int w = t >> 6, L = t & 63;

  floatx4 acc0 = {0.f, 0.f, 0.f, 0.f};
  floatx4 acc1 = {0.f, 0.f, 0.f, 0.f};

  int ar = t >> 2, akq = t & 3;          // A staging: row 0..63, k-chunk base
  int arow = rowBase + ar;
  int bn = t >> 3, bkq = t & 7;          // B staging: n 0..31, k-chunk 0..7
  long brow = (long)(colBase + bn) * K;

  for (int k0 = 0; k0 < K; k0 += 64) {
    // ---- stage A (two 16B chunks per thread) ----
#pragma unroll
    for (int half = 0; half < 2; half++) {
      int q = akq + half * 4;
      uint4 av = {0u, 0u, 0u, 0u};
      if (arow < M) {
        int gk = k0 + q * 8;
        if (AMODE == 0) {
          av = *(const uint4*)(A0 + (long)arow * K + gk);
        } else {
          int j = gk >> 8, kc = gk & 255;
          const ushort* src = (j == 0) ? A0 : (j == 1) ? A1 : (j == 2) ? A2 : A3;
          long rr = (j == 3) ? (long)batch[arow] : (long)arow;
          av = *(const uint4*)(src + rr * 256 + kc);
        }
      }
      *(uint4*)&As[q][ar][0] = av;
    }
    // ---- stage B (one 16B chunk per thread) ----
    {
      uint4 bv = *(const uint4*)(Bt + brow + k0 + bkq * 8);
      *(uint4*)&Bs[bkq][bn][0] = bv;
    }
    __syncthreads();
    // ---- compute: 8 k-chunks -> 2 per lane-quad, 4 MFMAs ----
    int mrow = w * 16 + (L & 15);
    int nlo = L & 15;
#pragma unroll
    for (int half = 0; half < 2; half++) {
      int q = (L >> 4) + half * 4;
      short8 af = *(const short8*)&As[q][mrow][0];
      short8 bf0 = *(const short8*)&Bs[q][nlo][0];
      short8 bf1 = *(const short8*)&Bs[q][16 + nlo][0];
      acc0 = __builtin_amdgcn_mfma_f32_16x16x32_bf16(af, bf0, acc0, 0, 0, 0);
      acc1 = __builtin_amdgcn_mfma_f32_16x16x32_bf16(af, bf1, acc1, 0, 0, 0);
    }
    __syncthreads();
  }
  // ---- epilogue: C/D layout col=lane&15, row=(lane>>4)*4+reg ----
  int col0 = colBase + (L & 15);
  int rbase = rowBase + w * 16 + (L >> 4) * 4;
  float b0 = bias ? bias[col0] : 0.f;
  float b1 = bias ? bias[col0 + 16] : 0.f;
#pragma unroll
  for (int r = 0; r < 4; r++) {
    int row = rbase + r;
    if (row >= M) continue;
    float v0 = acc0[r] + b0;
    float v1 = acc1[r] + b1;
    if (act == 1) {
      v0 = v0 > 0.f ? v0 : 0.01f * v0;
      v1 = v1 > 0.f ? v1 : 0.01f * v1;
    }
    C[(long)row * N + col0] = v0;
    C[(long)row * N + col0 + 16] = v1;
  }
}

// ---------------- fp32 tiled GEMM (kept for small MLP2) ----------------
__global__ __launch_bounds__(256) void gat_gemm(
    int M, int K, int Ncols, const float* __restrict__ Af,
    const float* __restrict__ Bw, const float* __restrict__ bias,
    float* __restrict__ Cout, int act) {
  __shared__ float As2[16][65];
  __shared__ float Bs2[16][65];
  int tid = threadIdx.x;
  int rowBase = blockIdx.y * 64;
  int colBase = blockIdx.x * 64;
  int ty = tid >> 4, tx = tid & 15;
  float acc[4][4] = {};
  for (int k0 = 0; k0 < K; k0 += 16) {
    {
      int r = tid >> 2;
      int kk = (tid & 3) * 4;
      int row = rowBase + r;
#pragma unroll
      for (int u = 0; u < 4; u++) {
        int k = k0 + kk + u;
        float v = 0.f;
        if (row < M && k < K) v = Af[(long)row * K + k];
        As2[kk + u][r] = v;
      }
    }
    {
      int kr = tid >> 4;
      int c = (tid & 15) * 4;
      int k = k0 + kr;
#pragma unroll
      for (int u = 0; u < 4; u++) {
        int col = colBase + c + u;
        float v = 0.f;
        if (k < K && col < Ncols) v = Bw[(long)k * Ncols + col];
        Bs2[kr][c + u] = v;
      }
    }
    __syncthreads();
#pragma unroll
    for (int kk = 0; kk < 16; kk++) {
      float ra[4], rb[4];
#pragma unroll
      for (int i = 0; i < 4; i++) ra[i] = As2[kk][ty * 4 + i];
#pragma unroll
      for (int j = 0; j < 4; j++) rb[j] = Bs2[kk][tx * 4 + j];
#pragma unroll
      for (int i = 0; i < 4; i++)
#pragma unroll
        for (int j = 0; j < 4; j++) acc[i][j] += ra[i] * rb[j];
    }
    __syncthreads();
  }
#pragma unroll
  for (int i = 0; i < 4; i++) {
    int row = rowBase + ty * 4 + i;
    if (row >= M) continue;
#pragma unroll
    for (int j = 0; j < 4; j++) {
      int col = colBase + tx * 4 + j;
      if (col >= Ncols) continue;
      float v = acc[i][j];
      if (bias) v += bias[col];
      if (act == 1) v = v > 0.f ? v : 0.01f * v;
      Cout[(long)row * Ncols + col] = v;
    }
  }
}

// ---------------- per-layer small kernels ----------------
// Q[c,h] = sum_d We[c, h*32+d] * ae[h,d]
__global__ void gat_make_q(const float* __restrict__ We,
                           const float* __restrict__ ae, float* __restrict__ Q) {
  int t = threadIdx.x;
  if (t >= kEd * kH) return;
  int c = t >> 3, h = t & 7;
  float s = 0.f;
#pragma unroll
  for (int d = 0; d < kD; d++) s += We[c * kC + h * kD + d] * ae[h * kD + d];
  Q[c * kH + h] = s;
}

// a_src[n,h] = xl[n,h,:].a_s[h,:] ; a_dst likewise
__global__ void gat_node_coef(const float* __restrict__ xl, const float* __restrict__ as_,
                              const float* __restrict__ ad_, float* __restrict__ a_src,
                              float* __restrict__ a_dst) {
  int t = blockIdx.x * blockDim.x + threadIdx.x;
  if (t >= kN * kH) return;
  int n = t >> 3, h = t & 7;
  const float* row = xl + (long)n * kC + h * kD;
  float ss = 0.f, sd = 0.f;
#pragma unroll
  for (int d = 0; d < kD; d++) {
    float v = row[d];
    ss += v * as_[h * kD + d];
    sd += v * ad_[h * kD + d];
  }
  a_src[t] = ss;
  a_dst[t] = sd;
}

// alpha[e,h] = leakyrelu_0.2( a_src[src] + a_dst[dst] + ea_row . Q[:,h] )
__global__ void gat_edge_alpha(const int* __restrict__ ei, const float* __restrict__ ea,
                               const float* __restrict__ ea_loop, const float* __restrict__ Q,
                               const float* __restrict__ a_src, const float* __restrict__ a_dst,
                               float* __restrict__ alpha) {
  int e = blockIdx.x * blockDim.x + threadIdx.x;
  if (e >= kEtot) return;
  int s, d;
  float eav[kEd];
  if (e < kE) {
    s = ei[e];
    d = ei[kE + e];
    const float4* r = (const float4*)(ea + (long)e * kEd);
#pragma unroll
    for (int q = 0; q < kEd / 4; q++) {
      float4 v = r[q];
      eav[q * 4 + 0] = v.x; eav[q * 4 + 1] = v.y;
      eav[q * 4 + 2] = v.z; eav[q * 4 + 3] = v.w;
    }
  } else {
    s = d = e - kE;
    const float* r = ea_loop + (long)s * kEd;
#pragma unroll
    for (int c = 0; c < kEd; c++) eav[c] = r[c];
  }
  const float* asr = a_src + s * kH;
  const float* adr = a_dst + d * kH;
#pragma unroll
  for (int h = 0; h < kH; h++) {
    float q = 0.f;
#pragma unroll
    for (int c = 0; c < kEd; c++) q += eav[c] * Q[c * kH + h];
    float a = asr[h] + adr[h] + q;
    a = a > 0.f ? a : 0.2f * a;
    alpha[(long)e * kH + h] = a;
  }
}

// per (node, head): segment softmax in place (alpha -> att)
__global__ void gat_softmax(const int* __restrict__ offs, const int* __restrict__ el,
                            float* __restrict__ alpha) {
  int t = blockIdx.x * blockDim.x + threadIdx.x;
  if (t >= kN * kH) return;
  int n = t >> 3, h = t & 7;
  int lo = offs[n], hi = offs[n + 1];
  float m = -1e30f;
  for (int j = lo; j < hi; j++) m = fmaxf(m, alpha[(long)el[j] * kH + h]);
  float s = 0.f;
  for (int j = lo; j < hi; j++) s += __expf(alpha[(long)el[j] * kH + h] - m);
  float inv = 1.f / s;
  for (int j = lo; j < hi; j++) {
    long idx = (long)el[j] * kH + h;
    alpha[idx] = __expf(alpha[idx] - m) * inv;
  }
}

// one wave per node: hb[n,c] = bf16( sum_e att[e, c/32] * xl[src_e, c] + b[c] )
__global__ __launch_bounds__(256) void gat_aggregate(
    const int* __restrict__ offs, const int* __restrict__ el, const int* __restrict__ ei,
    const float* __restrict__ alpha, const float* __restrict__ xl,
    const float* __restrict__ bias, ushort* __restrict__ hb) {
  int n = blockIdx.x * 4 + (threadIdx.x >> 6);
  if (n >= kN) return;
  int lane = threadIdx.x & 63;
  int c = lane * 4;
  int h = lane >> 3;
  int lo = offs[n], hi = offs[n + 1];
  float a0 = 0.f, a1 = 0.f, a2 = 0.f, a3 = 0.f;
  for (int j = lo; j < hi; j++) {
    int e = el[j];
    int s = (e < kE) ? ei[e] : (e - kE);
    float att = alpha[(long)e * kH + h];
    float4 v = *(const float4*)(xl + (long)s * kC + c);
    a0 += att * v.x; a1 += att * v.y; a2 += att * v.z; a3 += att * v.w;
  }
  ushort4 o;
  o.x = f2b(a0 + bias[c]);
  o.y = f2b(a1 + bias[c + 1]);
  o.z = f2b(a2 + bias[c + 2]);
  o.w = f2b(a3 + bias[c + 3]);
  *(ushort4*)(hb + (long)n * kC + c) = o;
}

// ---------------- pooling (batch sorted -> segmented reduce) ----------------
__global__ __launch_bounds__(256) void gat_pool_seg(const ushort* __restrict__ h3b,
                                                    const int* __restrict__ batch,
                                                    ushort* __restrict__ hpoolb) {
  int m = blockIdx.x;
  int c = threadIdx.x;
  int lo = 0, hi = kN;
  while (lo < hi) { int mid = (lo + hi) >> 1; if (batch[mid] < m) lo = mid + 1; else hi = mid; }
  int start = lo;
  hi = kN;
  while (lo < hi) { int mid = (lo + hi) >> 1; if (batch[mid] < m + 1) lo = mid + 1; else hi = mid; }
  int end = lo;
  float s = 0.f;
  for (int n = start; n < end; n++) s += b2f(h3b[(long)n * kC + c]);
  hpoolb[(long)m * kC + c] = f2b(s);
}

__global__ void gat_mlp3(const float* __restrict__ c2, const float* __restrict__ lw3,
                         const float* __restrict__ lb3, float* __restrict__ out) {
  int n = blockIdx.x * blockDim.x + threadIdx.x;
  if (n >= kN) return;
  float s = lb3[0];
  const float* r = c2 + (long)n * 64;
#pragma unroll
  for (int k = 0; k < 64; k++) s += r[k] * lw3[k];
  float v = 1.f / (1.f + __expf(-s));
  out[n] = v;
}

// ---------------- host ----------------
static inline int cdiv(int a, int b) { return (a + b - 1) / b; }

extern "C" void kernel_launch(void* const* d_in, const int* in_sizes, int n_in,
                              void* d_out, int out_size, void* d_ws, size_t ws_size,
                              hipStream_t stream) {
  (void)in_sizes; (void)n_in; (void)out_size; (void)ws_size;
  const float* x = (const float*)d_in[0];
  const int* ei = (const int*)d_in[1];
  const float* ea = (const float*)d_in[2];
  const int* batch = (const int*)d_in[3];
  const float *W[3], *as_[3], *ad_[3], *We_[3], *ae_[3], *bb[3];
  for (int l = 0; l < 3; l++) {
    W[l]   = (const float*)d_in[4 + 6 * l];
    as_[l] = (const float*)d_in[5 + 6 * l];
    ad_[l] = (const float*)d_in[6 + 6 * l];
    We_[l] = (const float*)d_in[7 + 6 * l];
    ae_[l] = (const float*)d_in[8 + 6 * l];
    bb[l]  = (const float*)d_in[9 + 6 * l];
  }
  const float* lw1 = (const float*)d_in[22];
  const float* lb1 = (const float*)d_in[23];
  const float* lw2 = (const float*)d_in[24];
  const float* lb2 = (const float*)d_in[25];
  const float* lw3 = (const float*)d_in[26];
  const float* lb3 = (const float*)d_in[27];
  float* out = (float*)d_out;

  char* p = (char*)d_ws;
  auto carve = [&](size_t bytes) -> void* {
    void* r = (void*)p;
    p += (bytes + 255) & ~(size_t)255;
    return r;
  };
  float* xl      = (float*)carve(sizeof(float) * (size_t)kN * kC);
  float* alpha   = (float*)carve(sizeof(float) * (size_t)kEtot * kH);
  float* a_src   = (float*)carve(sizeof(float) * (size_t)kN * kH);
  float* a_dst   = (float*)carve(sizeof(float) * (size_t)kN * kH);
  float* ea_loop = (float*)carve(sizeof(float) * (size_t)kN * kEd);
  float* Q       = (float*)carve(sizeof(float) * 128);
  ushort* xb     = (ushort*)carve(sizeof(ushort) * (size_t)kN * 64);
  ushort* h1b    = (ushort*)carve(sizeof(ushort) * (size_t)kN * kC);
  ushort* h2b    = (ushort*)carve(sizeof(ushort) * (size_t)kN * kC);
  ushort* h3b    = (ushort*)carve(sizeof(ushort) * (size_t)kN * kC);
  ushort* hpoolb = (ushort*)carve(sizeof(ushort) * (size_t)kNM * kC);
  ushort* Wt1    = (ushort*)carve(sizeof(ushort) * 64 * 256);
  ushort* Wt2    = (ushort*)carve(sizeof(ushort) * 256 * 256);
  ushort* Wt3    = (ushort*)carve(sizeof(ushort) * 256 * 256);
  ushort* lwt1   = (ushort*)carve(sizeof(ushort) * 1024 * 96);
  int* deg   = (int*)carve(sizeof(int) * kN);
  int* fillc = (int*)carve(sizeof(int) * kN);
  int* offs  = (int*)carve(sizeof(int) * (kN + 1));
  int* el    = (int*)carve(sizeof(int) * kEtot);
  // dead-buffer aliases for MLP intermediates
  float* c1 = alpha;  // N*96 floats <= Etot*8 floats
  float* c2 = xl;     // N*64  <= N*256

  // ---- zero counters ----
  gat_zero32<<<cdiv(kN, 256), 256, 0, stream>>>((unsigned int*)deg, kN);
  gat_zero32<<<cdiv(kN, 256), 256, 0, stream>>>((unsigned int*)fillc, kN);

  // ---- weight / input conversions (bf16, B pre-transposed to [N][K]) ----
  cvt_f2b<<<cdiv(kN * 64, 256), 256, 0, stream>>>(x, xb, kN * 64);
  cvt_wt<<<cdiv(64 * 256, 256), 256, 0, stream>>>(W[0], Wt1, 64, 256);
  cvt_wt<<<cdiv(256 * 256, 256), 256, 0, stream>>>(W[1], Wt2, 256, 256);
  cvt_wt<<<cdiv(256 * 256, 256), 256, 0, stream>>>(W[2], Wt3, 256, 256);
  cvt_wt<<<cdiv(1024 * 96, 256), 256, 0, stream>>>(lw1, lwt1, 1024, 96);

  // ---- CSR build + self-loop edge_attr (atomic-free) ----
  gat_count<<<cdiv(kE, 256), 256, 0, stream>>>(ei, deg);
  gat_scan<<<1, 1024, 0, stream>>>(deg, offs);
  gat_fill<<<cdiv(kEtot, 256), 256, 0, stream>>>(ei, offs, fillc, el);
  gat_ealoop<<<cdiv(kN * kEd, 256), 256, 0, stream>>>(offs, el, ea, ea_loop);

  // ---- 3 GAT layers ----
  const ushort* hinb[3] = {xb, h1b, h2b};
  ushort* houtb[3] = {h1b, h2b, h3b};
  const ushort* Wt[3] = {Wt1, Wt2, Wt3};
  int kdim[3] = {64, kC, kC};
  for (int l = 0; l < 3; l++) {
    dim3 ggrid(kC / 32, cdiv(kN, 64));
    gat_gemm_mfma<0><<<ggrid, 256, 0, stream>>>(kN, kdim[l], kC,
                                                hinb[l], nullptr, nullptr, nullptr, nullptr,
                                                Wt[l], nullptr, xl, 0);
    gat_make_q<<<1, 128, 0, stream>>>(We_[l], ae_[l], Q);
    gat_node_coef<<<cdiv(kN * kH, 256), 256, 0, stream>>>(xl, as_[l], ad_[l], a_src, a_dst);
    gat_edge_alpha<<<cdiv(kEtot, 256), 256, 0, stream>>>(ei, ea, ea_loop, Q, a_src, a_dst, alpha);
    gat_softmax<<<cdiv(kN * kH, 256), 256, 0, stream>>>(offs, el, alpha);
    gat_aggregate<<<cdiv(kN, 4), 256, 0, stream>>>(offs, el, ei, alpha, xl, bb[l], houtb[l]);
  }

  // ---- pooling (segmented, batch sorted) ----
  gat_pool_seg<<<kNM, kC, 0, stream>>>(h3b, batch, hpoolb);

  // ---- MLP ----
  {
    dim3 g1(96 / 32, cdiv(kN, 64));
    gat_gemm_mfma<2><<<g1, 256, 0, stream>>>(kN, 4 * kC, 96,
                                             h1b, h2b, h3b, hpoolb, batch,
                                             lwt1, lb1, c1, 1);
    dim3 g2(1, cdiv(kN, 64));
    gat_gemm<<<g2, 256, 0, stream>>>(kN, 96, 64, c1, lw2, lb2, c2, 1);
    gat_mlp3<<<cdiv(kN, 256), 256, 0, stream>>>(c2, lw3, lb3, out);
  }
}

// Round 6
// 1234.629 us; speedup vs baseline: 2.3181x; 1.1308x over previous
//
#include <hip/hip_runtime.h>
#include <hip/hip_bf16.h>

namespace {
constexpr int kN    = 50000;
constexpr int kE    = 800000;
constexpr int kEtot = kE + kN;   // 850000 (self-loops appended)
constexpr int kEd   = 16;
constexpr int kH    = 8;
constexpr int kD    = 32;
constexpr int kC    = kH * kD;   // 256
constexpr int kNM   = 500;
}

typedef __attribute__((ext_vector_type(8))) _Float16 half8;
typedef __attribute__((ext_vector_type(4))) float floatx4;

__device__ __forceinline__ float h2f(ushort u) {
  union { ushort u; _Float16 h; } v;
  v.u = u;
  return (float)v.h;
}
__device__ __forceinline__ ushort f2h(float f) {
  union { _Float16 h; ushort u; } v;
  v.h = (_Float16)f;  // v_cvt_f16_f32, RNE
  return v.u;
}

// ---------------- utility ----------------
__global__ void gat_zero32(unsigned int* p, int n) {
  int i = blockIdx.x * blockDim.x + threadIdx.x;
  if (i < n) p[i] = 0u;
}

// fp32 -> fp16 flat convert
__global__ void cvt_f2h(const float* __restrict__ in, ushort* __restrict__ out, int n) {
  int i = blockIdx.x * blockDim.x + threadIdx.x;
  if (i < n) out[i] = f2h(in[i]);
}

// Wt[n][k] = fp16(W[k][n]);  W is K x N fp32
__global__ void cvt_wt(const float* __restrict__ W, ushort* __restrict__ Wt, int K, int N) {
  int i = blockIdx.x * blockDim.x + threadIdx.x;
  if (i >= K * N) return;
  int n = i / K, k = i - n * K;
  Wt[i] = f2h(W[(long)k * N + n]);
}

// lw2[96][64] -> Wt2p[64][128] fp16 (K zero-padded 96->128)
__global__ void cvt_wt2p(const float* __restrict__ W, ushort* __restrict__ Wt) {
  int i = blockIdx.x * blockDim.x + threadIdx.x;
  if (i >= 64 * 128) return;
  int n = i >> 7, k = i & 127;
  Wt[i] = (k < 96) ? f2h(W[(long)k * 64 + n]) : (ushort)0;
}

// ---------------- CSR build (shared by all 3 layers) ----------------
__global__ void gat_count(const int* __restrict__ ei, int* __restrict__ deg) {
  int e = blockIdx.x * blockDim.x + threadIdx.x;
  if (e >= kE) return;
  atomicAdd(&deg[ei[kE + e]], 1);
}

__global__ void gat_scan(const int* __restrict__ deg, int* __restrict__ offs) {
  __shared__ int sums[1024];
  int t = threadIdx.x;
  constexpr int CH = (kN + 1023) / 1024;  // 49
  int lo = t * CH, hi = min(lo + CH, kN);
  int s = 0;
  for (int i = lo; i < hi; i++) s += deg[i] + 1;  // +1 self-loop
  sums[t] = s;
  __syncthreads();
  for (int off = 1; off < 1024; off <<= 1) {
    int v = (t >= off) ? sums[t - off] : 0;
    __syncthreads();
    sums[t] += v;
    __syncthreads();
  }
  int base = sums[t] - s;  // exclusive
  for (int i = lo; i < hi; i++) { offs[i] = base; base += deg[i] + 1; }
  if (t == 1023) offs[kN] = kEtot;
}

__global__ void gat_fill(const int* __restrict__ ei, const int* __restrict__ offs,
                         int* __restrict__ fillc, int* __restrict__ el) {
  int e = blockIdx.x * blockDim.x + threadIdx.x;
  if (e >= kEtot) return;
  int d = (e < kE) ? ei[kE + e] : (e - kE);
  int pos = offs[d] + atomicAdd(&fillc[d], 1);
  el[pos] = e;
}

// ea_loop[n,c] = sum over real in-edges e of ea[e,c]   (atomic-free CSR walk)
__global__ void gat_ealoop(const int* __restrict__ offs, const int* __restrict__ el,
                           const float* __restrict__ ea, float* __restrict__ ea_loop) {
  int t = blockIdx.x * blockDim.x + threadIdx.x;
  if (t >= kN * kEd) return;
  int n = t >> 4, c = t & 15;
  int lo = offs[n], hi = offs[n + 1];
  float s = 0.f;
  for (int j = lo; j < hi; j++) {
    int e = el[j];
    if (e < kE) s += ea[(long)e * kEd + c];
  }
  ea_loop[t] = s;
}

// ---------------- fp16 MFMA GEMM ----------------
// act( A(MxK,fp16 row-major) @ Bt^T + bias ) -> C fp32 (ldc) and/or Ch fp16 (ldch)
// Bt is pre-transposed [N][K] fp16.
// AMODE 0: A = A0 (row stride K).
// AMODE 2: A row r, col k: j=k>>8 -> {A0,A1,A2,A3[batch[r]]}, each row stride 256.
// Block: 256 thr = 4 waves; tile 64(M) x 64(N); BK=64. Wave w: rows w*16..+15, 4 col tiles.
template <int AMODE>
__global__ __launch_bounds__(256) void gat_gemm_mfma(
    int M, int K, int N,
    const ushort* __restrict__ A0, const ushort* __restrict__ A1,
    const ushort* __restrict__ A2, const ushort* __restrict__ A3,
    const int* __restrict__ batch,
    const ushort* __restrict__ Bt, const float* __restrict__ bias,
    float* __restrict__ C, int ldc, ushort* __restrict__ Ch, int ldch, int act) {
  __shared__ ushort As[8][64][8];  // 8 KB
  __shared__ ushort Bs[8][64][8];  // 8 KB
  int t = threadIdx.x;
  int rowBase = blockIdx.y * 64;
  int colBase = blockIdx.x * 64;
  int w = t >> 6, L = t & 63;

  floatx4 acc[4];
#pragma unroll
  for (int i = 0; i < 4; i++) acc[i] = (floatx4){0.f, 0.f, 0.f, 0.f};

  int ar = t >> 2, akq = t & 3;  // staging: row/n 0..63, k-chunk base 0..3
  int arow = rowBase + ar;
  int bok = (colBase + ar) < N;
  long brow = (long)(colBase + ar) * K;

  for (int k0 = 0; k0 < K; k0 += 64) {
#pragma unroll
    for (int half = 0; half < 2; half++) {
      int q = akq + half * 4;
      int gk = k0 + q * 8;
      // ---- stage A ----
      uint4 av = {0u, 0u, 0u, 0u};
      if (arow < M) {
        if (AMODE == 0) {
          av = *(const uint4*)(A0 + (long)arow * K + gk);
        } else {
          int j = gk >> 8, kc = gk & 255;
          const ushort* src = (j == 0) ? A0 : (j == 1) ? A1 : (j == 2) ? A2 : A3;
          long rr = (j == 3) ? (long)batch[arow] : (long)arow;
          av = *(const uint4*)(src + rr * 256 + kc);
        }
      }
      *(uint4*)&As[q][ar][0] = av;
      // ---- stage B ----
      uint4 bv = {0u, 0u, 0u, 0u};
      if (bok) bv = *(const uint4*)(Bt + brow + gk);
      *(uint4*)&Bs[q][ar][0] = bv;
    }
    __syncthreads();
    int mrow = w * 16 + (L & 15);
    int nlo = L & 15;
#pragma unroll
    for (int half = 0; half < 2; half++) {
      int q = (L >> 4) + half * 4;
      half8 af = *(const half8*)&As[q][mrow][0];
#pragma unroll
      for (int t4 = 0; t4 < 4; t4++) {
        half8 bf = *(const half8*)&Bs[q][t4 * 16 + nlo][0];
        acc[t4] = __builtin_amdgcn_mfma_f32_16x16x32_f16(af, bf, acc[t4], 0, 0, 0);
      }
    }
    __syncthreads();
  }
  // ---- epilogue: C/D layout col=lane&15, row=(lane>>4)*4+reg ----
  int nlo = L & 15;
  int rbase = rowBase + w * 16 + (L >> 4) * 4;
#pragma unroll
  for (int t4 = 0; t4 < 4; t4++) {
    int col = colBase + t4 * 16 + nlo;
    if (col >= N) continue;
    float bv = bias ? bias[col] : 0.f;
#pragma unroll
    for (int r = 0; r < 4; r++) {
      int row = rbase + r;
      if (row >= M) continue;
      float v = acc[t4][r] + bv;
      if (act == 1) v = v > 0.f ? v : 0.01f * v;
      if (C) C[(long)row * ldc + col] = v;
      if (Ch) Ch[(long)row * ldch + col] = f2h(v);
    }
  }
}

// ---------------- per-layer small kernels ----------------
// Q[c,h] = sum_d We[c, h*32+d] * ae[h,d]
__global__ void gat_make_q(const float* __restrict__ We,
                           const float* __restrict__ ae, float* __restrict__ Q) {
  int t = threadIdx.x;
  if (t >= kEd * kH) return;
  int c = t >> 3, h = t & 7;
  float s = 0.f;
#pragma unroll
  for (int d = 0; d < kD; d++) s += We[c * kC + h * kD + d] * ae[h * kD + d];
  Q[c * kH + h] = s;
}

// a_src[n,h] = xl[n,h,:].a_s[h,:] ; a_dst likewise   (fp32 path)
__global__ void gat_node_coef(const float* __restrict__ xl, const float* __restrict__ as_,
                              const float* __restrict__ ad_, float* __restrict__ a_src,
                              float* __restrict__ a_dst) {
  int t = blockIdx.x * blockDim.x + threadIdx.x;
  if (t >= kN * kH) return;
  int n = t >> 3, h = t & 7;
  const float* row = xl + (long)n * kC + h * kD;
  float ss = 0.f, sd = 0.f;
#pragma unroll
  for (int d = 0; d < kD; d++) {
    float v = row[d];
    ss += v * as_[h * kD + d];
    sd += v * ad_[h * kD + d];
  }
  a_src[t] = ss;
  a_dst[t] = sd;
}

// alpha[e,h] = leakyrelu_0.2( a_src[src] + a_dst[dst] + ea_row . Q[:,h] )
__global__ void gat_edge_alpha(const int* __restrict__ ei, const float* __restrict__ ea,
                               const float* __restrict__ ea_loop, const float* __restrict__ Q,
                               const float* __restrict__ a_src, const float* __restrict__ a_dst,
                               float* __restrict__ alpha) {
  int e = blockIdx.x * blockDim.x + threadIdx.x;
  if (e >= kEtot) return;
  int s, d;
  float eav[kEd];
  if (e < kE) {
    s = ei[e];
    d = ei[kE + e];
    const float4* r = (const float4*)(ea + (long)e * kEd);
#pragma unroll
    for (int q = 0; q < kEd / 4; q++) {
      float4 v = r[q];
      eav[q * 4 + 0] = v.x; eav[q * 4 + 1] = v.y;
      eav[q * 4 + 2] = v.z; eav[q * 4 + 3] = v.w;
    }
  } else {
    s = d = e - kE;
    const float* r = ea_loop + (long)s * kEd;
#pragma unroll
    for (int c = 0; c < kEd; c++) eav[c] = r[c];
  }
  const float* asr = a_src + s * kH;
  const float* adr = a_dst + d * kH;
#pragma unroll
  for (int h = 0; h < kH; h++) {
    float q = 0.f;
#pragma unroll
    for (int c = 0; c < kEd; c++) q += eav[c] * Q[c * kH + h];
    float a = asr[h] + adr[h] + q;
    a = a > 0.f ? a : 0.2f * a;
    alpha[(long)e * kH + h] = a;
  }
}

// per (node, head): compute segment max + denom; sm[t] = (m, 1/den)
__global__ void gat_softmax_md(const int* __restrict__ offs, const int* __restrict__ el,
                               const float* __restrict__ alpha, float2* __restrict__ sm) {
  int t = blockIdx.x * blockDim.x + threadIdx.x;
  if (t >= kN * kH) return;
  int n = t >> 3, h = t & 7;
  int lo = offs[n], hi = offs[n + 1];
  float m = -1e30f;
  for (int j = lo; j < hi; j++) m = fmaxf(m, alpha[(long)el[j] * kH + h]);
  float s = 0.f;
  for (int j = lo; j < hi; j++) s += __expf(alpha[(long)el[j] * kH + h] - m);
  sm[t] = make_float2(m, 1.f / s);
}

// one wave per node: hh[n,c] = fp16( sum_e softmax(alpha)[e,h] * xlh[src_e,c] + b[c] )
__global__ __launch_bounds__(256) void gat_aggregate(
    const int* __restrict__ offs, const int* __restrict__ el, const int* __restrict__ ei,
    const float* __restrict__ alpha, const float2* __restrict__ sm,
    const ushort* __restrict__ xlh, const float* __restrict__ bias,
    ushort* __restrict__ hh) {
  int n = blockIdx.x * 4 + (threadIdx.x >> 6);
  if (n >= kN) return;
  int lane = threadIdx.x & 63;
  int c = lane * 4;
  int h = lane >> 3;
  int lo = offs[n], hi = offs[n + 1];
  float2 md = sm[n * kH + h];
  float a0 = 0.f, a1 = 0.f, a2 = 0.f, a3 = 0.f;
  for (int j = lo; j < hi; j++) {
    int e = el[j];
    int s = (e < kE) ? ei[e] : (e - kE);
    float att = __expf(alpha[(long)e * kH + h] - md.x) * md.y;
    ushort4 v = *(const ushort4*)(xlh + (long)s * kC + c);
    a0 += att * h2f(v.x); a1 += att * h2f(v.y);
    a2 += att * h2f(v.z); a3 += att * h2f(v.w);
  }
  ushort4 o;
  o.x = f2h(a0 + bias[c]);
  o.y = f2h(a1 + bias[c + 1]);
  o.z = f2h(a2 + bias[c + 2]);
  o.w = f2h(a3 + bias[c + 3]);
  *(ushort4*)(hh + (long)n * kC + c) = o;
}

// ---------------- pooling (batch sorted -> segmented reduce) ----------------
__global__ __launch_bounds__(256) void gat_pool_seg(const ushort* __restrict__ h3h,
                                                    const int* __restrict__ batch,
                                                    ushort* __restrict__ hpoolh) {
  int m = blockIdx.x;
  int c = threadIdx.x;
  int lo = 0, hi = kN;
  while (lo < hi) { int mid = (lo + hi) >> 1; if (batch[mid] < m) lo = mid + 1; else hi = mid; }
  int start = lo;
  hi = kN;
  while (lo < hi) { int mid = (lo + hi) >> 1; if (batch[mid] < m + 1) lo = mid + 1; else hi = mid; }
  int end = lo;
  float s = 0.f;
  for (int n = start; n < end; n++) s += h2f(h3h[(long)n * kC + c]);
  hpoolh[(long)m * kC + c] = f2h(s);
}

__global__ void gat_mlp3(const float* __restrict__ c2, const float* __restrict__ lw3,
                         const float* __restrict__ lb3, float* __restrict__ out) {
  int n = blockIdx.x * blockDim.x + threadIdx.x;
  if (n >= kN) return;
  float s = lb3[0];
  const float* r = c2 + (long)n * 64;
#pragma unroll
  for (int k = 0; k < 64; k++) s += r[k] * lw3[k];
  float v = 1.f / (1.f + __expf(-s));
  out[n] = v;
}

// ---------------- host ----------------
static inline int cdiv(int a, int b) { return (a + b - 1) / b; }

extern "C" void kernel_launch(void* const* d_in, const int* in_sizes, int n_in,
                              void* d_out, int out_size, void* d_ws, size_t ws_size,
                              hipStream_t stream) {
  (void)in_sizes; (void)n_in; (void)out_size; (void)ws_size;
  const float* x = (const float*)d_in[0];
  const int* ei = (const int*)d_in[1];
  const float* ea = (const float*)d_in[2];
  const int* batch = (const int*)d_in[3];
  const float *W[3], *as_[3], *ad_[3], *We_[3], *ae_[3], *bb[3];
  for (int l = 0; l < 3; l++) {
    W[l]   = (const float*)d_in[4 + 6 * l];
    as_[l] = (const float*)d_in[5 + 6 * l];
    ad_[l] = (const float*)d_in[6 + 6 * l];
    We_[l] = (const float*)d_in[7 + 6 * l];
    ae_[l] = (const float*)d_in[8 + 6 * l];
    bb[l]  = (const float*)d_in[9 + 6 * l];
  }
  const float* lw1 = (const float*)d_in[22];
  const float* lb1 = (const float*)d_in[23];
  const float* lw2 = (const float*)d_in[24];
  const float* lb2 = (const float*)d_in[25];
  const float* lw3 = (const float*)d_in[26];
  const float* lb3 = (const float*)d_in[27];
  float* out = (float*)d_out;

  char* p = (char*)d_ws;
  auto carve = [&](size_t bytes) -> void* {
    void* r = (void*)p;
    p += (bytes + 255) & ~(size_t)255;
    return r;
  };
  float* xl      = (float*)carve(sizeof(float) * (size_t)kN * kC);
  float* alpha   = (float*)carve(sizeof(float) * (size_t)kEtot * kH);
  float* a_src   = (float*)carve(sizeof(float) * (size_t)kN * kH);
  float* a_dst   = (float*)carve(sizeof(float) * (size_t)kN * kH);
  float2* sm     = (float2*)carve(sizeof(float2) * (size_t)kN * kH);
  float* ea_loop = (float*)carve(sizeof(float) * (size_t)kN * kEd);
  float* Q       = (float*)carve(sizeof(float) * 128);
  ushort* xh     = (ushort*)carve(sizeof(ushort) * (size_t)kN * 64);
  ushort* xlh    = (ushort*)carve(sizeof(ushort) * (size_t)kN * kC);
  ushort* h1h    = (ushort*)carve(sizeof(ushort) * (size_t)kN * kC);
  ushort* h2h    = (ushort*)carve(sizeof(ushort) * (size_t)kN * kC);
  ushort* h3h    = (ushort*)carve(sizeof(ushort) * (size_t)kN * kC);
  ushort* hpoolh = (ushort*)carve(sizeof(ushort) * (size_t)kNM * kC);
  ushort* Wt1    = (ushort*)carve(sizeof(ushort) * 64 * 256);
  ushort* Wt2    = (ushort*)carve(sizeof(ushort) * 256 * 256);
  ushort* Wt3    = (ushort*)carve(sizeof(ushort) * 256 * 256);
  ushort* lwt1   = (ushort*)carve(sizeof(ushort) * 1024 * 96);
  ushort* lwt2p  = (ushort*)carve(sizeof(ushort) * 64 * 128);
  int* deg   = (int*)carve(sizeof(int) * kN);
  int* fillc = (int*)carve(sizeof(int) * kN);
  int* offs  = (int*)carve(sizeof(int) * (kN + 1));
  int* el    = (int*)carve(sizeof(int) * kEtot);
  // dead-buffer aliases for MLP intermediates (layers finished by then)
  ushort* c1h = (ushort*)alpha;  // kN*128 ushorts (12.8MB) <= alpha (27MB)
  float* c2 = xl;                // kN*64 floats <= kN*256

  // ---- zero counters ----
  gat_zero32<<<cdiv(kN, 256), 256, 0, stream>>>((unsigned int*)deg, kN);
  gat_zero32<<<cdiv(kN, 256), 256, 0, stream>>>((unsigned int*)fillc, kN);

  // ---- weight / input conversions (fp16, B pre-transposed to [N][K]) ----
  cvt_f2h<<<cdiv(kN * 64, 256), 256, 0, stream>>>(x, xh, kN * 64);
  cvt_wt<<<cdiv(64 * 256, 256), 256, 0, stream>>>(W[0], Wt1, 64, 256);
  cvt_wt<<<cdiv(256 * 256, 256), 256, 0, stream>>>(W[1], Wt2, 256, 256);
  cvt_wt<<<cdiv(256 * 256, 256), 256, 0, stream>>>(W[2], Wt3, 256, 256);
  cvt_wt<<<cdiv(1024 * 96, 256), 256, 0, stream>>>(lw1, lwt1, 1024, 96);
  cvt_wt2p<<<cdiv(64 * 128, 256), 256, 0, stream>>>(lw2, lwt2p);

  // ---- CSR build + self-loop edge_attr (atomic-free) ----
  gat_count<<<cdiv(kE, 256), 256, 0, stream>>>(ei, deg);
  gat_scan<<<1, 1024, 0, stream>>>(deg, offs);
  gat_fill<<<cdiv(kEtot, 256), 256, 0, stream>>>(ei, offs, fillc, el);
  gat_ealoop<<<cdiv(kN * kEd, 256), 256, 0, stream>>>(offs, el, ea, ea_loop);

  // ---- 3 GAT layers ----
  const ushort* hinh[3] = {xh, h1h, h2h};
  ushort* houth[3] = {h1h, h2h, h3h};
  const ushort* Wt[3] = {Wt1, Wt2, Wt3};
  int kdim[3] = {64, kC, kC};
  for (int l = 0; l < 3; l++) {
    dim3 ggrid(kC / 64, cdiv(kN, 64));
    gat_gemm_mfma<0><<<ggrid, 256, 0, stream>>>(kN, kdim[l], kC,
                                                hinh[l], nullptr, nullptr, nullptr, nullptr,
                                                Wt[l], nullptr,
                                                xl, kC, xlh, kC, 0);
    gat_make_q<<<1, 128, 0, stream>>>(We_[l], ae_[l], Q);
    gat_node_coef<<<cdiv(kN * kH, 256), 256, 0, stream>>>(xl, as_[l], ad_[l], a_src, a_dst);
    gat_edge_alpha<<<cdiv(kEtot, 256), 256, 0, stream>>>(ei, ea, ea_loop, Q, a_src, a_dst, alpha);
    gat_softmax_md<<<cdiv(kN * kH, 256), 256, 0, stream>>>(offs, el, alpha, sm);
    gat_aggregate<<<cdiv(kN, 4), 256, 0, stream>>>(offs, el, ei, alpha, sm, xlh, bb[l], houth[l]);
  }

  // ---- pooling (segmented, batch sorted) ----
  gat_pool_seg<<<kNM, kC, 0, stream>>>(h3h, batch, hpoolh);

  // ---- MLP ----
  {
    // zero c1h (padded K 96->128)
    gat_zero32<<<cdiv(kN * 64, 256), 256, 0, stream>>>((unsigned int*)c1h, kN * 64);
    dim3 g1(cdiv(96, 64), cdiv(kN, 64));
    gat_gemm_mfma<2><<<g1, 256, 0, stream>>>(kN, 4 * kC, 96,
                                             h1h, h2h, h3h, hpoolh, batch,
                                             lwt1, lb1,
                                             nullptr, 0, c1h, 128, 1);
    dim3 g2(1, cdiv(kN, 64));
    gat_gemm_mfma<0><<<g2, 256, 0, stream>>>(kN, 128, 64,
                                             c1h, nullptr, nullptr, nullptr, nullptr,
                                             lwt2p, lb2,
                                             c2, 64, nullptr, 0, 1);
    gat_mlp3<<<cdiv(kN, 256), 256, 0, stream>>>(c2, lw3, lb3, out);
  }
}

// Round 7
// 925.356 us; speedup vs baseline: 3.0929x; 1.3342x over previous
//
#include <hip/hip_runtime.h>
#include <hip/hip_bf16.h>

namespace {
constexpr int kN    = 50000;
constexpr int kE    = 800000;
constexpr int kEtot = kE + kN;   // 850000 (self-loops appended)
constexpr int kEd   = 16;
constexpr int kH    = 8;
constexpr int kD    = 32;
constexpr int kC    = kH * kD;   // 256
constexpr int kNM   = 500;
}

typedef __attribute__((ext_vector_type(8))) _Float16 half8;
typedef __attribute__((ext_vector_type(4))) float floatx4;
typedef __attribute__((ext_vector_type(8))) ushort ushort8v;

__device__ __forceinline__ float h2f(ushort u) {
  union { ushort u; _Float16 h; } v;
  v.u = u;
  return (float)v.h;
}
__device__ __forceinline__ ushort f2h(float f) {
  union { _Float16 h; ushort u; } v;
  v.h = (_Float16)f;  // v_cvt_f16_f32, RNE
  return v.u;
}

// ---------------- merged small kernels ----------------
__global__ void gat_zero2(int* __restrict__ a, int* __restrict__ b, int n) {
  int i = blockIdx.x * blockDim.x + threadIdx.x;
  if (i < n) { a[i] = 0; b[i] = 0; }
}

// zero pad cols 96..127 of c1h[kN][128] (fp16)
__global__ void gat_zeropad(ushort* __restrict__ c1h) {
  int i = blockIdx.x * blockDim.x + threadIdx.x;
  if (i >= kN * 4) return;
  int row = i >> 2, q = i & 3;
  uint4 z = {0u, 0u, 0u, 0u};
  *(uint4*)(c1h + (long)row * 128 + 96 + q * 8) = z;
}

// all fp32->fp16 conversions in one launch.
// ranges: xh[kN*64], Wt1[256][64], Wt2[256][256], Wt3[256][256], lwt1[96][1024], lwt2p[64][128]
__global__ void cvt_all(const float* __restrict__ x,
                        const float* __restrict__ W1, const float* __restrict__ W2,
                        const float* __restrict__ W3, const float* __restrict__ lw1,
                        const float* __restrict__ lw2,
                        ushort* __restrict__ xh, ushort* __restrict__ Wt1,
                        ushort* __restrict__ Wt2, ushort* __restrict__ Wt3,
                        ushort* __restrict__ lwt1, ushort* __restrict__ lwt2p) {
  int i = blockIdx.x * blockDim.x + threadIdx.x;
  if (i < kN * 64) { xh[i] = f2h(x[i]); return; }
  i -= kN * 64;
  if (i < 256 * 64) {  // Wt1[n][k], W1 is 64x256
    int n = i >> 6, k = i & 63;
    Wt1[i] = f2h(W1[(long)k * 256 + n]);
    return;
  }
  i -= 256 * 64;
  if (i < 256 * 256) {
    int n = i >> 8, k = i & 255;
    Wt2[i] = f2h(W2[(long)k * 256 + n]);
    return;
  }
  i -= 256 * 256;
  if (i < 256 * 256) {
    int n = i >> 8, k = i & 255;
    Wt3[i] = f2h(W3[(long)k * 256 + n]);
    return;
  }
  i -= 256 * 256;
  if (i < 96 * 1024) {  // lwt1[n][k], lw1 is 1024x96
    int n = i >> 10, k = i & 1023;
    lwt1[i] = f2h(lw1[(long)k * 96 + n]);
    return;
  }
  i -= 96 * 1024;
  if (i < 64 * 128) {  // lwt2p[n][k], K zero-padded 96->128; lw2 is 96x64
    int n = i >> 7, k = i & 127;
    lwt2p[i] = (k < 96) ? f2h(lw2[(long)k * 64 + n]) : (ushort)0;
    return;
  }
}

// Q3[l][c][h] = sum_d We_l[c, h*32+d] * ae_l[h,d]   (one launch, 384 threads)
__global__ void gat_make_q3(const float* __restrict__ We1, const float* __restrict__ ae1,
                            const float* __restrict__ We2, const float* __restrict__ ae2,
                            const float* __restrict__ We3, const float* __restrict__ ae3,
                            float* __restrict__ Q3) {
  int t = threadIdx.x;
  if (t >= 384) return;
  int l = t >> 7, r = t & 127;
  const float* We = (l == 0) ? We1 : (l == 1) ? We2 : We3;
  const float* ae = (l == 0) ? ae1 : (l == 1) ? ae2 : ae3;
  int c = r >> 3, h = r & 7;
  float s = 0.f;
#pragma unroll
  for (int d = 0; d < kD; d++) s += We[c * kC + h * kD + d] * ae[h * kD + d];
  Q3[l * 128 + c * kH + h] = s;
}

// ---------------- CSR build (shared by all 3 layers) ----------------
__global__ void gat_count(const int* __restrict__ ei, int* __restrict__ deg) {
  int e = blockIdx.x * blockDim.x + threadIdx.x;
  if (e >= kE) return;
  atomicAdd(&deg[ei[kE + e]], 1);
}

__global__ void gat_scan(const int* __restrict__ deg, int* __restrict__ offs) {
  __shared__ int sums[1024];
  int t = threadIdx.x;
  constexpr int CH = (kN + 1023) / 1024;  // 49
  int lo = t * CH, hi = min(lo + CH, kN);
  int s = 0;
  for (int i = lo; i < hi; i++) s += deg[i] + 1;  // +1 self-loop
  sums[t] = s;
  __syncthreads();
  for (int off = 1; off < 1024; off <<= 1) {
    int v = (t >= off) ? sums[t - off] : 0;
    __syncthreads();
    sums[t] += v;
    __syncthreads();
  }
  int base = sums[t] - s;  // exclusive
  for (int i = lo; i < hi; i++) { offs[i] = base; base += deg[i] + 1; }
  if (t == 1023) offs[kN] = kEtot;
}

// el[pos]=edge id (for ealoop); esrc[pos]=source node; epos[e]=pos (for alpha scatter)
__global__ void gat_fill(const int* __restrict__ ei, const int* __restrict__ offs,
                         int* __restrict__ fillc, int* __restrict__ el,
                         int* __restrict__ esrc, int* __restrict__ epos) {
  int e = blockIdx.x * blockDim.x + threadIdx.x;
  if (e >= kEtot) return;
  int s, d;
  if (e < kE) { s = ei[e]; d = ei[kE + e]; }
  else { s = d = e - kE; }
  int pos = offs[d] + atomicAdd(&fillc[d], 1);
  el[pos] = e;
  esrc[pos] = s;
  epos[e] = pos;
}

// ea_loop[n,c] = sum over real in-edges e of ea[e,c]   (atomic-free CSR walk)
__global__ void gat_ealoop(const int* __restrict__ offs, const int* __restrict__ el,
                           const float* __restrict__ ea, float* __restrict__ ea_loop) {
  int t = blockIdx.x * blockDim.x + threadIdx.x;
  if (t >= kN * kEd) return;
  int n = t >> 4, c = t & 15;
  int lo = offs[n], hi = offs[n + 1];
  float s = 0.f;
  for (int j = lo; j < hi; j++) {
    int e = el[j];
    if (e < kE) s += ea[(long)e * kEd + c];
  }
  ea_loop[t] = s;
}

// ---------------- fp16 MFMA GEMM ----------------
// act( A(MxK,fp16 row-major) @ Bt^T + bias ) -> C fp32 (ldc) and/or Ch fp16 (ldch)
// Bt pre-transposed [N][K] fp16.
// AMODE 0: A = A0 (row stride K).
// AMODE 2: A row r, col k: j=k>>8 -> {A0,A1,A2,A3[batch[r]]}, each row stride 256.
// COEF 1: additionally emit a_src[row,h]=xl_row_h . as_[h], a_dst likewise (N must be 256;
//         block's 64 cols = heads (colBase>>5), (colBase>>5)+1; reduced over 16 lanes).
// Block: 256 thr = 4 waves; tile 64(M) x 64(N); BK=64.
template <int AMODE, int COEF>
__global__ __launch_bounds__(256) void gat_gemm_mfma(
    int M, int K, int N,
    const ushort* __restrict__ A0, const ushort* __restrict__ A1,
    const ushort* __restrict__ A2, const ushort* __restrict__ A3,
    const int* __restrict__ batch,
    const ushort* __restrict__ Bt, const float* __restrict__ bias,
    float* __restrict__ C, int ldc, ushort* __restrict__ Ch, int ldch, int act,
    const float* __restrict__ as_, const float* __restrict__ ad_,
    float* __restrict__ a_src, float* __restrict__ a_dst) {
  __shared__ ushort As[8][64][8];  // 8 KB
  __shared__ ushort Bs[8][64][8];  // 8 KB
  int t = threadIdx.x;
  int rowBase = blockIdx.y * 64;
  int colBase = blockIdx.x * 64;
  int w = t >> 6, L = t & 63;

  floatx4 acc[4];
#pragma unroll
  for (int i = 0; i < 4; i++) acc[i] = (floatx4){0.f, 0.f, 0.f, 0.f};

  int ar = t >> 2, akq = t & 3;  // staging: row/n 0..63, k-chunk base 0..3
  int arow = rowBase + ar;
  int bok = (colBase + ar) < N;
  long brow = (long)(colBase + ar) * K;

  for (int k0 = 0; k0 < K; k0 += 64) {
#pragma unroll
    for (int half = 0; half < 2; half++) {
      int q = akq + half * 4;
      int gk = k0 + q * 8;
      // ---- stage A ----
      uint4 av = {0u, 0u, 0u, 0u};
      if (arow < M) {
        if (AMODE == 0) {
          av = *(const uint4*)(A0 + (long)arow * K + gk);
        } else {
          int j = gk >> 8, kc = gk & 255;
          const ushort* src = (j == 0) ? A0 : (j == 1) ? A1 : (j == 2) ? A2 : A3;
          long rr = (j == 3) ? (long)batch[arow] : (long)arow;
          av = *(const uint4*)(src + rr * 256 + kc);
        }
      }
      *(uint4*)&As[q][ar][0] = av;
      // ---- stage B ----
      uint4 bv = {0u, 0u, 0u, 0u};
      if (bok) bv = *(const uint4*)(Bt + brow + gk);
      *(uint4*)&Bs[q][ar][0] = bv;
    }
    __syncthreads();
    int mrow = w * 16 + (L & 15);
    int nl = L & 15;
#pragma unroll
    for (int half = 0; half < 2; half++) {
      int q = (L >> 4) + half * 4;
      half8 af = *(const half8*)&As[q][mrow][0];
#pragma unroll
      for (int t4 = 0; t4 < 4; t4++) {
        half8 bf = *(const half8*)&Bs[q][t4 * 16 + nl][0];
        acc[t4] = __builtin_amdgcn_mfma_f32_16x16x32_f16(af, bf, acc[t4], 0, 0, 0);
      }
    }
    __syncthreads();
  }
  // ---- epilogue: C/D layout col=lane&15, row=(lane>>4)*4+reg ----
  int nlo = L & 15;
  int rbase = rowBase + w * 16 + (L >> 4) * 4;
#pragma unroll
  for (int t4 = 0; t4 < 4; t4++) {
    int col = colBase + t4 * 16 + nlo;
    if (col >= N) continue;
    float bv = bias ? bias[col] : 0.f;
#pragma unroll
    for (int r = 0; r < 4; r++) {
      int row = rbase + r;
      if (row >= M) continue;
      float v = acc[t4][r] + bv;
      if (act == 1) v = v > 0.f ? v : 0.01f * v;
      if (C) C[(long)row * ldc + col] = v;
      if (Ch) Ch[(long)row * ldch + col] = f2h(v);
    }
  }
  if (COEF) {
    // per-row head dots from fp32 accumulators; heads hA=colBase>>5 (t4 0,1), hA+1 (t4 2,3)
    float ps[2][4], pd[2][4];
#pragma unroll
    for (int g = 0; g < 2; g++)
#pragma unroll
      for (int r = 0; r < 4; r++) { ps[g][r] = 0.f; pd[g][r] = 0.f; }
    int hA = colBase >> 5;
#pragma unroll
    for (int t4 = 0; t4 < 4; t4++) {
      int g = t4 >> 1;
      int widx = (t4 & 1) * 16 + nlo;
      float wsv = as_[(hA + g) * kD + widx];
      float wdv = ad_[(hA + g) * kD + widx];
#pragma unroll
      for (int r = 0; r < 4; r++) {
        ps[g][r] += acc[t4][r] * wsv;
        pd[g][r] += acc[t4][r] * wdv;
      }
    }
#pragma unroll
    for (int m = 1; m < 16; m <<= 1) {
#pragma unroll
      for (int g = 0; g < 2; g++)
#pragma unroll
        for (int r = 0; r < 4; r++) {
          ps[g][r] += __shfl_xor(ps[g][r], m);
          pd[g][r] += __shfl_xor(pd[g][r], m);
        }
    }
    if (nlo == 0) {
#pragma unroll
      for (int r = 0; r < 4; r++) {
        int row = rbase + r;
        if (row >= M) continue;
        a_src[row * kH + hA] = ps[0][r];
        a_src[row * kH + hA + 1] = ps[1][r];
        a_dst[row * kH + hA] = pd[0][r];
        a_dst[row * kH + hA + 1] = pd[1][r];
      }
    }
  }
}

// ---------------- per-layer small kernels ----------------
// alpha_csr[epos[e]*8+h] = leakyrelu_0.2( a_src[src,h] + a_dst[dst,h] + ea_row . Q[:,h] )
__global__ void gat_edge_alpha(const int* __restrict__ ei, const float* __restrict__ ea,
                               const float* __restrict__ ea_loop, const float* __restrict__ Q,
                               const float* __restrict__ a_src, const float* __restrict__ a_dst,
                               const int* __restrict__ epos, float* __restrict__ alpha_csr) {
  int e = blockIdx.x * blockDim.x + threadIdx.x;
  if (e >= kEtot) return;
  int s, d;
  float eav[kEd];
  if (e < kE) {
    s = ei[e];
    d = ei[kE + e];
    const float4* r = (const float4*)(ea + (long)e * kEd);
#pragma unroll
    for (int q = 0; q < kEd / 4; q++) {
      float4 v = r[q];
      eav[q * 4 + 0] = v.x; eav[q * 4 + 1] = v.y;
      eav[q * 4 + 2] = v.z; eav[q * 4 + 3] = v.w;
    }
  } else {
    s = d = e - kE;
    const float* r = ea_loop + (long)s * kEd;
#pragma unroll
    for (int c = 0; c < kEd; c++) eav[c] = r[c];
  }
  const float* asr = a_src + s * kH;
  const float* adr = a_dst + d * kH;
  float av[kH];
#pragma unroll
  for (int h = 0; h < kH; h++) {
    float q = 0.f;
#pragma unroll
    for (int c = 0; c < kEd; c++) q += eav[c] * Q[c * kH + h];
    float a = asr[h] + adr[h] + q;
    av[h] = a > 0.f ? a : 0.2f * a;
  }
  long base = (long)epos[e] * kH;
  *(float4*)(alpha_csr + base) = make_float4(av[0], av[1], av[2], av[3]);
  *(float4*)(alpha_csr + base + 4) = make_float4(av[4], av[5], av[6], av[7]);
}

// per (node, head): segment max + denom over CSR-contiguous logits; sm = (m, 1/den)
__global__ void gat_softmax_md(const int* __restrict__ offs, const float* __restrict__ alpha_csr,
                               float2* __restrict__ sm) {
  int t = blockIdx.x * blockDim.x + threadIdx.x;
  if (t >= kN * kH) return;
  int n = t >> 3, h = t & 7;
  int lo = offs[n], hi = offs[n + 1];
  float m = -1e30f;
  for (int j = lo; j < hi; j++) m = fmaxf(m, alpha_csr[(long)j * kH + h]);
  float s = 0.f;
  for (int j = lo; j < hi; j++) s += __expf(alpha_csr[(long)j * kH + h] - m);
  sm[t] = make_float2(m, 1.f / s);
}

// one wave per node, half-wave per edge (2 edges/iter, 16B/lane gathers):
// hh[n,c] = fp16( sum_j softmax(alpha)[j,h] * xlh[esrc[j],c] + b[c] )
__global__ __launch_bounds__(256) void gat_aggregate(
    const int* __restrict__ offs, const int* __restrict__ esrc,
    const float* __restrict__ alpha_csr, const float2* __restrict__ sm,
    const ushort* __restrict__ xlh, const float* __restrict__ bias,
    ushort* __restrict__ hh) {
  int n = blockIdx.x * 4 + (threadIdx.x >> 6);
  if (n >= kN) return;
  int L = threadIdx.x & 63;
  int eh = L >> 5;        // which edge of the pair
  int cl = L & 31;
  int c = cl * 8;         // 8 channels per lane
  int h = cl >> 2;
  int lo = offs[n], hi = offs[n + 1];
  float2 md = sm[n * kH + h];
  float acc[8] = {0.f, 0.f, 0.f, 0.f, 0.f, 0.f, 0.f, 0.f};
  for (int j = lo; j < hi; j += 2) {
    int jj = j + eh;
    bool valid = jj < hi;
    int js = valid ? jj : lo;
    int s = esrc[js];
    float att = valid ? __expf(alpha_csr[(long)jj * kH + h] - md.x) * md.y : 0.f;
    ushort8v v = *(const ushort8v*)(xlh + (long)s * kC + c);
#pragma unroll
    for (int i = 0; i < 8; i++) acc[i] += att * h2f(v[i]);
  }
#pragma unroll
  for (int i = 0; i < 8; i++) acc[i] += __shfl_xor(acc[i], 32);
  if (eh == 0) {
    float4 b0 = *(const float4*)(bias + c);
    float4 b1 = *(const float4*)(bias + c + 4);
    ushort8v o;
    o[0] = f2h(acc[0] + b0.x); o[1] = f2h(acc[1] + b0.y);
    o[2] = f2h(acc[2] + b0.z); o[3] = f2h(acc[3] + b0.w);
    o[4] = f2h(acc[4] + b1.x); o[5] = f2h(acc[5] + b1.y);
    o[6] = f2h(acc[6] + b1.z); o[7] = f2h(acc[7] + b1.w);
    *(ushort8v*)(hh + (long)n * kC + c) = o;
  }
}

// ---------------- pooling (batch sorted -> segmented reduce) ----------------
__global__ __launch_bounds__(256) void gat_pool_seg(const ushort* __restrict__ h3h,
                                                    const int* __restrict__ batch,
                                                    ushort* __restrict__ hpoolh) {
  int m = blockIdx.x;
  int c = threadIdx.x;
  int lo = 0, hi = kN;
  while (lo < hi) { int mid = (lo + hi) >> 1; if (batch[mid] < m) lo = mid + 1; else hi = mid; }
  int start = lo;
  hi = kN;
  while (lo < hi) { int mid = (lo + hi) >> 1; if (batch[mid] < m + 1) lo = mid + 1; else hi = mid; }
  int end = lo;
  float s = 0.f;
  for (int n = start; n < end; n++) s += h2f(h3h[(long)n * kC + c]);
  hpoolh[(long)m * kC + c] = f2h(s);
}

__global__ void gat_mlp3(const float* __restrict__ c2, const float* __restrict__ lw3,
                         const float* __restrict__ lb3, float* __restrict__ out) {
  int n = blockIdx.x * blockDim.x + threadIdx.x;
  if (n >= kN) return;
  float s = lb3[0];
  const float* r = c2 + (long)n * 64;
#pragma unroll
  for (int k = 0; k < 64; k++) s += r[k] * lw3[k];
  float v = 1.f / (1.f + __expf(-s));
  out[n] = v;
}

// ---------------- host ----------------
static inline int cdiv(int a, int b) { return (a + b - 1) / b; }

extern "C" void kernel_launch(void* const* d_in, const int* in_sizes, int n_in,
                              void* d_out, int out_size, void* d_ws, size_t ws_size,
                              hipStream_t stream) {
  (void)in_sizes; (void)n_in; (void)out_size; (void)ws_size;
  const float* x = (const float*)d_in[0];
  const int* ei = (const int*)d_in[1];
  const float* ea = (const float*)d_in[2];
  const int* batch = (const int*)d_in[3];
  const float *W[3], *as_[3], *ad_[3], *We_[3], *ae_[3], *bb[3];
  for (int l = 0; l < 3; l++) {
    W[l]   = (const float*)d_in[4 + 6 * l];
    as_[l] = (const float*)d_in[5 + 6 * l];
    ad_[l] = (const float*)d_in[6 + 6 * l];
    We_[l] = (const float*)d_in[7 + 6 * l];
    ae_[l] = (const float*)d_in[8 + 6 * l];
    bb[l]  = (const float*)d_in[9 + 6 * l];
  }
  const float* lw1 = (const float*)d_in[22];
  const float* lb1 = (const float*)d_in[23];
  const float* lw2 = (const float*)d_in[24];
  const float* lb2 = (const float*)d_in[25];
  const float* lw3 = (const float*)d_in[26];
  const float* lb3 = (const float*)d_in[27];
  float* out = (float*)d_out;

  char* p = (char*)d_ws;
  auto carve = [&](size_t bytes) -> void* {
    void* r = (void*)p;
    p += (bytes + 255) & ~(size_t)255;
    return r;
  };
  float* alpha_csr = (float*)carve(sizeof(float) * (size_t)kEtot * kH);
  float* a_src   = (float*)carve(sizeof(float) * (size_t)kN * kH);
  float* a_dst   = (float*)carve(sizeof(float) * (size_t)kN * kH);
  float2* sm     = (float2*)carve(sizeof(float2) * (size_t)kN * kH);
  float* ea_loop = (float*)carve(sizeof(float) * (size_t)kN * kEd);
  float* Q3      = (float*)carve(sizeof(float) * 3 * 128);
  float* c2      = (float*)carve(sizeof(float) * (size_t)kN * 64);
  ushort* xh     = (ushort*)carve(sizeof(ushort) * (size_t)kN * 64);
  ushort* xlh    = (ushort*)carve(sizeof(ushort) * (size_t)kN * kC);
  ushort* h1h    = (ushort*)carve(sizeof(ushort) * (size_t)kN * kC);
  ushort* h2h    = (ushort*)carve(sizeof(ushort) * (size_t)kN * kC);
  ushort* h3h    = (ushort*)carve(sizeof(ushort) * (size_t)kN * kC);
  ushort* hpoolh = (ushort*)carve(sizeof(ushort) * (size_t)kNM * kC);
  ushort* Wt1    = (ushort*)carve(sizeof(ushort) * 64 * 256);
  ushort* Wt2    = (ushort*)carve(sizeof(ushort) * 256 * 256);
  ushort* Wt3    = (ushort*)carve(sizeof(ushort) * 256 * 256);
  ushort* lwt1   = (ushort*)carve(sizeof(ushort) * 1024 * 96);
  ushort* lwt2p  = (ushort*)carve(sizeof(ushort) * 64 * 128);
  int* deg   = (int*)carve(sizeof(int) * kN);
  int* fillc = (int*)carve(sizeof(int) * kN);
  int* offs  = (int*)carve(sizeof(int) * (kN + 1));
  int* el    = (int*)carve(sizeof(int) * kEtot);
  int* esrc  = (int*)carve(sizeof(int) * kEtot);
  int* epos  = (int*)carve(sizeof(int) * kEtot);
  // dead-buffer alias: MLP1 intermediate (alpha_csr dead after layer 3)
  ushort* c1h = (ushort*)alpha_csr;  // kN*128 ushorts (12.8MB) <= 27.2MB

  // ---- zero counters + conversions + Q ----
  gat_zero2<<<cdiv(kN, 256), 256, 0, stream>>>(deg, fillc, kN);
  {
    int tot = kN * 64 + 256 * 64 + 2 * 256 * 256 + 96 * 1024 + 64 * 128;
    cvt_all<<<cdiv(tot, 256), 256, 0, stream>>>(x, W[0], W[1], W[2], lw1, lw2,
                                                xh, Wt1, Wt2, Wt3, lwt1, lwt2p);
  }
  gat_make_q3<<<1, 384, 0, stream>>>(We_[0], ae_[0], We_[1], ae_[1], We_[2], ae_[2], Q3);

  // ---- CSR build + self-loop edge_attr (atomic-free) ----
  gat_count<<<cdiv(kE, 256), 256, 0, stream>>>(ei, deg);
  gat_scan<<<1, 1024, 0, stream>>>(deg, offs);
  gat_fill<<<cdiv(kEtot, 256), 256, 0, stream>>>(ei, offs, fillc, el, esrc, epos);
  gat_ealoop<<<cdiv(kN * kEd, 256), 256, 0, stream>>>(offs, el, ea, ea_loop);

  // ---- 3 GAT layers ----
  const ushort* hinh[3] = {xh, h1h, h2h};
  ushort* houth[3] = {h1h, h2h, h3h};
  const ushort* Wt[3] = {Wt1, Wt2, Wt3};
  int kdim[3] = {64, kC, kC};
  for (int l = 0; l < 3; l++) {
    dim3 ggrid(kC / 64, cdiv(kN, 64));
    gat_gemm_mfma<0, 1><<<ggrid, 256, 0, stream>>>(
        kN, kdim[l], kC, hinh[l], nullptr, nullptr, nullptr, nullptr,
        Wt[l], nullptr, nullptr, 0, xlh, kC, 0,
        as_[l], ad_[l], a_src, a_dst);
    gat_edge_alpha<<<cdiv(kEtot, 256), 256, 0, stream>>>(ei, ea, ea_loop, Q3 + l * 128,
                                                         a_src, a_dst, epos, alpha_csr);
    gat_softmax_md<<<cdiv(kN * kH, 256), 256, 0, stream>>>(offs, alpha_csr, sm);
    gat_aggregate<<<cdiv(kN, 4), 256, 0, stream>>>(offs, esrc, alpha_csr, sm, xlh,
                                                   bb[l], houth[l]);
  }

  // ---- pooling (segmented, batch sorted) ----
  gat_pool_seg<<<kNM, kC, 0, stream>>>(h3h, batch, hpoolh);

  // ---- MLP ----
  {
    gat_zeropad<<<cdiv(kN * 4, 256), 256, 0, stream>>>(c1h);
    dim3 g1(cdiv(96, 64), cdiv(kN, 64));
    gat_gemm_mfma<2, 0><<<g1, 256, 0, stream>>>(
        kN, 4 * kC, 96, h1h, h2h, h3h, hpoolh, batch,
        lwt1, lb1, nullptr, 0, c1h, 128, 1,
        nullptr, nullptr, nullptr, nullptr);
    dim3 g2(1, cdiv(kN, 64));
    gat_gemm_mfma<0, 0><<<g2, 256, 0, stream>>>(
        kN, 128, 64, c1h, nullptr, nullptr, nullptr, nullptr,
        lwt2p, lb2, c2, 64, nullptr, 0, 1,
        nullptr, nullptr, nullptr, nullptr);
    gat_mlp3<<<cdiv(kN, 256), 256, 0, stream>>>(c2, lw3, lb3, out);
  }
}

// Round 8
// 831.931 us; speedup vs baseline: 3.4402x; 1.1123x over previous
//
#include <hip/hip_runtime.h>
#include <hip/hip_bf16.h>

namespace {
constexpr int kN    = 50000;
constexpr int kE    = 800000;
constexpr int kEtot = kE + kN;   // 850000 (self-loops appended)
constexpr int kEd   = 16;
constexpr int kH    = 8;
constexpr int kD    = 32;
constexpr int kC    = kH * kD;   // 256
constexpr int kNM   = 500;
constexpr int kNB   = (kN + 255) / 256;  // 196 scan blocks
}

typedef __attribute__((ext_vector_type(8))) _Float16 half8;
typedef __attribute__((ext_vector_type(4))) float floatx4;
typedef __attribute__((ext_vector_type(8))) ushort ushort8v;

__device__ __forceinline__ float h2f(ushort u) {
  union { ushort u; _Float16 h; } v;
  v.u = u;
  return (float)v.h;
}
__device__ __forceinline__ ushort f2h(float f) {
  union { _Float16 h; ushort u; } v;
  v.h = (_Float16)f;  // v_cvt_f16_f32, RNE
  return v.u;
}

// ---------------- merged small kernels ----------------
__global__ void gat_zero2(int* __restrict__ a, int* __restrict__ b, int n) {
  int i = blockIdx.x * blockDim.x + threadIdx.x;
  if (i < n) { a[i] = 0; b[i] = 0; }
}

// zero pad cols 96..127 of c1h[kN][128] (fp16)
__global__ void gat_zeropad(ushort* __restrict__ c1h) {
  int i = blockIdx.x * blockDim.x + threadIdx.x;
  if (i >= kN * 4) return;
  int row = i >> 2, q = i & 3;
  uint4 z = {0u, 0u, 0u, 0u};
  *(uint4*)(c1h + (long)row * 128 + 96 + q * 8) = z;
}

// all fp32->fp16 conversions in one launch.
__global__ void cvt_all(const float* __restrict__ x,
                        const float* __restrict__ W1, const float* __restrict__ W2,
                        const float* __restrict__ W3, const float* __restrict__ lw1,
                        const float* __restrict__ lw2,
                        ushort* __restrict__ xh, ushort* __restrict__ Wt1,
                        ushort* __restrict__ Wt2, ushort* __restrict__ Wt3,
                        ushort* __restrict__ lwt1, ushort* __restrict__ lwt2p) {
  int i = blockIdx.x * blockDim.x + threadIdx.x;
  if (i < kN * 64) { xh[i] = f2h(x[i]); return; }
  i -= kN * 64;
  if (i < 256 * 64) {  // Wt1[n][k], W1 is 64x256
    int n = i >> 6, k = i & 63;
    Wt1[i] = f2h(W1[(long)k * 256 + n]);
    return;
  }
  i -= 256 * 64;
  if (i < 256 * 256) {
    int n = i >> 8, k = i & 255;
    Wt2[i] = f2h(W2[(long)k * 256 + n]);
    return;
  }
  i -= 256 * 256;
  if (i < 256 * 256) {
    int n = i >> 8, k = i & 255;
    Wt3[i] = f2h(W3[(long)k * 256 + n]);
    return;
  }
  i -= 256 * 256;
  if (i < 96 * 1024) {  // lwt1[n][k], lw1 is 1024x96
    int n = i >> 10, k = i & 1023;
    lwt1[i] = f2h(lw1[(long)k * 96 + n]);
    return;
  }
  i -= 96 * 1024;
  if (i < 64 * 128) {  // lwt2p[n][k], K zero-padded 96->128; lw2 is 96x64
    int n = i >> 7, k = i & 127;
    lwt2p[i] = (k < 96) ? f2h(lw2[(long)k * 64 + n]) : (ushort)0;
    return;
  }
}

// Q3[l][c][h] = sum_d We_l[c, h*32+d] * ae_l[h,d]   (one launch, 384 threads)
__global__ void gat_make_q3(const float* __restrict__ We1, const float* __restrict__ ae1,
                            const float* __restrict__ We2, const float* __restrict__ ae2,
                            const float* __restrict__ We3, const float* __restrict__ ae3,
                            float* __restrict__ Q3) {
  int t = threadIdx.x;
  if (t >= 384) return;
  int l = t >> 7, r = t & 127;
  const float* We = (l == 0) ? We1 : (l == 1) ? We2 : We3;
  const float* ae = (l == 0) ? ae1 : (l == 1) ? ae2 : ae3;
  int c = r >> 3, h = r & 7;
  float s = 0.f;
#pragma unroll
  for (int d = 0; d < kD; d++) s += We[c * kC + h * kD + d] * ae[h * kD + d];
  Q3[l * 128 + c * kH + h] = s;
}

// ---------------- CSR build (shared by all 3 layers) ----------------
__global__ void gat_count(const int* __restrict__ ei, int* __restrict__ deg) {
  int e = blockIdx.x * blockDim.x + threadIdx.x;
  if (e >= kE) return;
  atomicAdd(&deg[ei[kE + e]], 1);
}

// hierarchical scan of (deg[i]+1): a) per-block local exclusive scan + block sums
__global__ __launch_bounds__(256) void gat_scan_a(const int* __restrict__ deg,
                                                  int* __restrict__ offs,
                                                  int* __restrict__ bsum) {
  __shared__ int s[256];
  int b = blockIdx.x, t = threadIdx.x;
  int i = b * 256 + t;
  int v = (i < kN) ? deg[i] + 1 : 0;
  s[t] = v;
  __syncthreads();
  for (int o = 1; o < 256; o <<= 1) {
    int u = (t >= o) ? s[t - o] : 0;
    __syncthreads();
    s[t] += u;
    __syncthreads();
  }
  if (i < kN) offs[i] = s[t] - v;
  if (t == 255) bsum[b] = s[255];
}

// b) single-block exclusive scan of the 196 block sums
__global__ __launch_bounds__(256) void gat_scan_b(const int* __restrict__ bsum,
                                                  int* __restrict__ bpre) {
  __shared__ int s[256];
  int t = threadIdx.x;
  int v = (t < kNB) ? bsum[t] : 0;
  s[t] = v;
  __syncthreads();
  for (int o = 1; o < 256; o <<= 1) {
    int u = (t >= o) ? s[t - o] : 0;
    __syncthreads();
    s[t] += u;
    __syncthreads();
  }
  if (t < kNB) bpre[t] = s[t] - v;
}

// c) add block prefixes; total is the compile-time constant kEtot
__global__ void gat_scan_c(int* __restrict__ offs, const int* __restrict__ bpre) {
  int i = blockIdx.x * blockDim.x + threadIdx.x;
  if (i < kN) offs[i] += bpre[blockIdx.x];
  if (i == 0) offs[kN] = kEtot;
}

// el[pos]=edge id (for ealoop); esrc[pos]=source node; epos[e]=pos (for alpha scatter)
__global__ void gat_fill(const int* __restrict__ ei, const int* __restrict__ offs,
                         int* __restrict__ fillc, int* __restrict__ el,
                         int* __restrict__ esrc, int* __restrict__ epos) {
  int e = blockIdx.x * blockDim.x + threadIdx.x;
  if (e >= kEtot) return;
  int s, d;
  if (e < kE) { s = ei[e]; d = ei[kE + e]; }
  else { s = d = e - kE; }
  int pos = offs[d] + atomicAdd(&fillc[d], 1);
  el[pos] = e;
  esrc[pos] = s;
  epos[e] = pos;
}

// ea_loop[n,c] = sum over real in-edges e of ea[e,c]   (atomic-free CSR walk)
__global__ void gat_ealoop(const int* __restrict__ offs, const int* __restrict__ el,
                           const float* __restrict__ ea, float* __restrict__ ea_loop) {
  int t = blockIdx.x * blockDim.x + threadIdx.x;
  if (t >= kN * kEd) return;
  int n = t >> 4, c = t & 15;
  int lo = offs[n], hi = offs[n + 1];
  float s = 0.f;
  for (int j = lo; j < hi; j++) {
    int e = el[j];
    if (e < kE) s += ea[(long)e * kEd + c];
  }
  ea_loop[t] = s;
}

// ---------------- fp16 MFMA GEMM ----------------
// act( A(MxK,fp16 row-major) @ Bt^T + bias ) -> C fp32 (ldc) and/or Ch fp16 (ldch)
// Bt pre-transposed [N][K] fp16.
// AMODE 0: A = A0 (row stride K).
// AMODE 2: A row r, col k: j=k>>8 -> {A0,A1,A2,A3[batch[r]]}, each row stride 256.
// COEF 1: additionally emit a_src[row,h]=xl_row_h . as_[h], a_dst likewise.
template <int AMODE, int COEF>
__global__ __launch_bounds__(256) void gat_gemm_mfma(
    int M, int K, int N,
    const ushort* __restrict__ A0, const ushort* __restrict__ A1,
    const ushort* __restrict__ A2, const ushort* __restrict__ A3,
    const int* __restrict__ batch,
    const ushort* __restrict__ Bt, const float* __restrict__ bias,
    float* __restrict__ C, int ldc, ushort* __restrict__ Ch, int ldch, int act,
    const float* __restrict__ as_, const float* __restrict__ ad_,
    float* __restrict__ a_src, float* __restrict__ a_dst) {
  __shared__ ushort As[8][64][8];  // 8 KB
  __shared__ ushort Bs[8][64][8];  // 8 KB
  int t = threadIdx.x;
  int rowBase = blockIdx.y * 64;
  int colBase = blockIdx.x * 64;
  int w = t >> 6, L = t & 63;

  floatx4 acc[4];
#pragma unroll
  for (int i = 0; i < 4; i++) acc[i] = (floatx4){0.f, 0.f, 0.f, 0.f};

  int ar = t >> 2, akq = t & 3;  // staging: row/n 0..63, k-chunk base 0..3
  int arow = rowBase + ar;
  int bok = (colBase + ar) < N;
  long brow = (long)(colBase + ar) * K;

  for (int k0 = 0; k0 < K; k0 += 64) {
#pragma unroll
    for (int half = 0; half < 2; half++) {
      int q = akq + half * 4;
      int gk = k0 + q * 8;
      // ---- stage A ----
      uint4 av = {0u, 0u, 0u, 0u};
      if (arow < M) {
        if (AMODE == 0) {
          av = *(const uint4*)(A0 + (long)arow * K + gk);
        } else {
          int j = gk >> 8, kc = gk & 255;
          const ushort* src = (j == 0) ? A0 : (j == 1) ? A1 : (j == 2) ? A2 : A3;
          long rr = (j == 3) ? (long)batch[arow] : (long)arow;
          av = *(const uint4*)(src + rr * 256 + kc);
        }
      }
      *(uint4*)&As[q][ar][0] = av;
      // ---- stage B ----
      uint4 bv = {0u, 0u, 0u, 0u};
      if (bok) bv = *(const uint4*)(Bt + brow + gk);
      *(uint4*)&Bs[q][ar][0] = bv;
    }
    __syncthreads();
    int mrow = w * 16 + (L & 15);
    int nl = L & 15;
#pragma unroll
    for (int half = 0; half < 2; half++) {
      int q = (L >> 4) + half * 4;
      half8 af = *(const half8*)&As[q][mrow][0];
#pragma unroll
      for (int t4 = 0; t4 < 4; t4++) {
        half8 bf = *(const half8*)&Bs[q][t4 * 16 + nl][0];
        acc[t4] = __builtin_amdgcn_mfma_f32_16x16x32_f16(af, bf, acc[t4], 0, 0, 0);
      }
    }
    __syncthreads();
  }
  // ---- epilogue: C/D layout col=lane&15, row=(lane>>4)*4+reg ----
  int nlo = L & 15;
  int rbase = rowBase + w * 16 + (L >> 4) * 4;
#pragma unroll
  for (int t4 = 0; t4 < 4; t4++) {
    int col = colBase + t4 * 16 + nlo;
    if (col >= N) continue;
    float bv = bias ? bias[col] : 0.f;
#pragma unroll
    for (int r = 0; r < 4; r++) {
      int row = rbase + r;
      if (row >= M) continue;
      float v = acc[t4][r] + bv;
      if (act == 1) v = v > 0.f ? v : 0.01f * v;
      if (C) C[(long)row * ldc + col] = v;
      if (Ch) Ch[(long)row * ldch + col] = f2h(v);
    }
  }
  if (COEF) {
    // per-row head dots from fp32 accumulators; heads hA=colBase>>5 (t4 0,1), hA+1 (t4 2,3)
    float ps[2][4], pd[2][4];
#pragma unroll
    for (int g = 0; g < 2; g++)
#pragma unroll
      for (int r = 0; r < 4; r++) { ps[g][r] = 0.f; pd[g][r] = 0.f; }
    int hA = colBase >> 5;
#pragma unroll
    for (int t4 = 0; t4 < 4; t4++) {
      int g = t4 >> 1;
      int widx = (t4 & 1) * 16 + nlo;
      float wsv = as_[(hA + g) * kD + widx];
      float wdv = ad_[(hA + g) * kD + widx];
#pragma unroll
      for (int r = 0; r < 4; r++) {
        ps[g][r] += acc[t4][r] * wsv;
        pd[g][r] += acc[t4][r] * wdv;
      }
    }
#pragma unroll
    for (int m = 1; m < 16; m <<= 1) {
#pragma unroll
      for (int g = 0; g < 2; g++)
#pragma unroll
        for (int r = 0; r < 4; r++) {
          ps[g][r] += __shfl_xor(ps[g][r], m);
          pd[g][r] += __shfl_xor(pd[g][r], m);
        }
    }
    if (nlo == 0) {
#pragma unroll
      for (int r = 0; r < 4; r++) {
        int row = rbase + r;
        if (row >= M) continue;
        a_src[row * kH + hA] = ps[0][r];
        a_src[row * kH + hA + 1] = ps[1][r];
        a_dst[row * kH + hA] = pd[0][r];
        a_dst[row * kH + hA + 1] = pd[1][r];
      }
    }
  }
}

// ---------------- per-layer small kernels ----------------
// alpha_csr[epos[e]*8+h] = leakyrelu_0.2( a_src[src,h] + a_dst[dst,h] + ea_row . Q[:,h] )
__global__ void gat_edge_alpha(const int* __restrict__ ei, const float* __restrict__ ea,
                               const float* __restrict__ ea_loop, const float* __restrict__ Q,
                               const float* __restrict__ a_src, const float* __restrict__ a_dst,
                               const int* __restrict__ epos, float* __restrict__ alpha_csr) {
  int e = blockIdx.x * blockDim.x + threadIdx.x;
  if (e >= kEtot) return;
  int s, d;
  float eav[kEd];
  if (e < kE) {
    s = ei[e];
    d = ei[kE + e];
    const float4* r = (const float4*)(ea + (long)e * kEd);
#pragma unroll
    for (int q = 0; q < kEd / 4; q++) {
      float4 v = r[q];
      eav[q * 4 + 0] = v.x; eav[q * 4 + 1] = v.y;
      eav[q * 4 + 2] = v.z; eav[q * 4 + 3] = v.w;
    }
  } else {
    s = d = e - kE;
    const float* r = ea_loop + (long)s * kEd;
#pragma unroll
    for (int c = 0; c < kEd; c++) eav[c] = r[c];
  }
  const float* asr = a_src + s * kH;
  const float* adr = a_dst + d * kH;
  float av[kH];
#pragma unroll
  for (int h = 0; h < kH; h++) {
    float q = 0.f;
#pragma unroll
    for (int c = 0; c < kEd; c++) q += eav[c] * Q[c * kH + h];
    float a = asr[h] + adr[h] + q;
    av[h] = a > 0.f ? a : 0.2f * a;
  }
  long base = (long)epos[e] * kH;
  *(float4*)(alpha_csr + base) = make_float4(av[0], av[1], av[2], av[3]);
  *(float4*)(alpha_csr + base + 4) = make_float4(av[4], av[5], av[6], av[7]);
}

// one wave per node; fused segment-softmax + aggregation.
// prepass: lane = (slice sl=L>>3, head hp=L&7), online (m,s); butterfly combine over slices.
// main: half-wave per edge (2 edges/iter, 16B/lane gathers).
__global__ __launch_bounds__(256) void gat_aggregate(
    const int* __restrict__ offs, const int* __restrict__ esrc,
    const float* __restrict__ alpha_csr,
    const ushort* __restrict__ xlh, const float* __restrict__ bias,
    ushort* __restrict__ hh) {
  int n = blockIdx.x * 4 + (threadIdx.x >> 6);
  if (n >= kN) return;
  int L = threadIdx.x & 63;
  int lo = offs[n], hi = offs[n + 1];
  // ---- fused per-head (max, sum) ----
  int hp = L & 7, sl = L >> 3;
  float m = -1e30f, s = 0.f;
  for (int j = lo + sl; j < hi; j += 8) {
    float a = alpha_csr[(long)j * kH + hp];
    if (a > m) { s = s * __expf(m - a) + 1.f; m = a; }
    else s += __expf(a - m);
  }
#pragma unroll
  for (int msk = 8; msk < 64; msk <<= 1) {
    float om = __shfl_xor(m, msk);
    float os = __shfl_xor(s, msk);
    float nm = fmaxf(m, om);
    s = s * __expf(m - nm) + os * __expf(om - nm);
    m = nm;
  }
  int eh = L >> 5;        // which edge of the pair
  int cl = L & 31;
  int c = cl * 8;         // 8 channels per lane
  int h = cl >> 2;
  float mh = __shfl(m, h);
  float invs = 1.f / __shfl(s, h);
  float acc[8] = {0.f, 0.f, 0.f, 0.f, 0.f, 0.f, 0.f, 0.f};
  for (int j = lo; j < hi; j += 2) {
    int jj = j + eh;
    bool valid = jj < hi;
    int js = valid ? jj : lo;
    int sn = esrc[js];
    float att = valid ? __expf(alpha_csr[(long)jj * kH + h] - mh) * invs : 0.f;
    ushort8v v = *(const ushort8v*)(xlh + (long)sn * kC + c);
#pragma unroll
    for (int i = 0; i < 8; i++) acc[i] += att * h2f(v[i]);
  }
#pragma unroll
  for (int i = 0; i < 8; i++) acc[i] += __shfl_xor(acc[i], 32);
  if (eh == 0) {
    float4 b0 = *(const float4*)(bias + c);
    float4 b1 = *(const float4*)(bias + c + 4);
    ushort8v o;
    o[0] = f2h(acc[0] + b0.x); o[1] = f2h(acc[1] + b0.y);
    o[2] = f2h(acc[2] + b0.z); o[3] = f2h(acc[3] + b0.w);
    o[4] = f2h(acc[4] + b1.x); o[5] = f2h(acc[5] + b1.y);
    o[6] = f2h(acc[6] + b1.z); o[7] = f2h(acc[7] + b1.w);
    *(ushort8v*)(hh + (long)n * kC + c) = o;
  }
}

// ---------------- pooling (batch sorted -> segmented reduce) ----------------
__global__ __launch_bounds__(256) void gat_pool_seg(const ushort* __restrict__ h3h,
                                                    const int* __restrict__ batch,
                                                    ushort* __restrict__ hpoolh) {
  int m = blockIdx.x;
  int c = threadIdx.x;
  int lo = 0, hi = kN;
  while (lo < hi) { int mid = (lo + hi) >> 1; if (batch[mid] < m) lo = mid + 1; else hi = mid; }
  int start = lo;
  hi = kN;
  while (lo < hi) { int mid = (lo + hi) >> 1; if (batch[mid] < m + 1) lo = mid + 1; else hi = mid; }
  int end = lo;
  float s = 0.f;
  for (int n = start; n < end; n++) s += h2f(h3h[(long)n * kC + c]);
  hpoolh[(long)m * kC + c] = f2h(s);
}

__global__ void gat_mlp3(const float* __restrict__ c2, const float* __restrict__ lw3,
                         const float* __restrict__ lb3, float* __restrict__ out) {
  int n = blockIdx.x * blockDim.x + threadIdx.x;
  if (n >= kN) return;
  float s = lb3[0];
  const float* r = c2 + (long)n * 64;
#pragma unroll
  for (int k = 0; k < 64; k++) s += r[k] * lw3[k];
  float v = 1.f / (1.f + __expf(-s));
  out[n] = v;
}

// ---------------- host ----------------
static inline int cdiv(int a, int b) { return (a + b - 1) / b; }

extern "C" void kernel_launch(void* const* d_in, const int* in_sizes, int n_in,
                              void* d_out, int out_size, void* d_ws, size_t ws_size,
                              hipStream_t stream) {
  (void)in_sizes; (void)n_in; (void)out_size; (void)ws_size;
  const float* x = (const float*)d_in[0];
  const int* ei = (const int*)d_in[1];
  const float* ea = (const float*)d_in[2];
  const int* batch = (const int*)d_in[3];
  const float *W[3], *as_[3], *ad_[3], *We_[3], *ae_[3], *bb[3];
  for (int l = 0; l < 3; l++) {
    W[l]   = (const float*)d_in[4 + 6 * l];
    as_[l] = (const float*)d_in[5 + 6 * l];
    ad_[l] = (const float*)d_in[6 + 6 * l];
    We_[l] = (const float*)d_in[7 + 6 * l];
    ae_[l] = (const float*)d_in[8 + 6 * l];
    bb[l]  = (const float*)d_in[9 + 6 * l];
  }
  const float* lw1 = (const float*)d_in[22];
  const float* lb1 = (const float*)d_in[23];
  const float* lw2 = (const float*)d_in[24];
  const float* lb2 = (const float*)d_in[25];
  const float* lw3 = (const float*)d_in[26];
  const float* lb3 = (const float*)d_in[27];
  float* out = (float*)d_out;

  char* p = (char*)d_ws;
  auto carve = [&](size_t bytes) -> void* {
    void* r = (void*)p;
    p += (bytes + 255) & ~(size_t)255;
    return r;
  };
  float* alpha_csr = (float*)carve(sizeof(float) * (size_t)kEtot * kH);
  float* a_src   = (float*)carve(sizeof(float) * (size_t)kN * kH);
  float* a_dst   = (float*)carve(sizeof(float) * (size_t)kN * kH);
  float* ea_loop = (float*)carve(sizeof(float) * (size_t)kN * kEd);
  float* Q3      = (float*)carve(sizeof(float) * 3 * 128);
  float* c2      = (float*)carve(sizeof(float) * (size_t)kN * 64);
  ushort* xh     = (ushort*)carve(sizeof(ushort) * (size_t)kN * 64);
  ushort* xlh    = (ushort*)carve(sizeof(ushort) * (size_t)kN * kC);
  ushort* h1h    = (ushort*)carve(sizeof(ushort) * (size_t)kN * kC);
  ushort* h2h    = (ushort*)carve(sizeof(ushort) * (size_t)kN * kC);
  ushort* h3h    = (ushort*)carve(sizeof(ushort) * (size_t)kN * kC);
  ushort* hpoolh = (ushort*)carve(sizeof(ushort) * (size_t)kNM * kC);
  ushort* Wt1    = (ushort*)carve(sizeof(ushort) * 64 * 256);
  ushort* Wt2    = (ushort*)carve(sizeof(ushort) * 256 * 256);
  ushort* Wt3    = (ushort*)carve(sizeof(ushort) * 256 * 256);
  ushort* lwt1   = (ushort*)carve(sizeof(ushort) * 1024 * 96);
  ushort* lwt2p  = (ushort*)carve(sizeof(ushort) * 64 * 128);
  int* deg   = (int*)carve(sizeof(int) * kN);
  int* fillc = (int*)carve(sizeof(int) * kN);
  int* offs  = (int*)carve(sizeof(int) * (kN + 1));
  int* bsum  = (int*)carve(sizeof(int) * 256);
  int* bpre  = (int*)carve(sizeof(int) * 256);
  int* el    = (int*)carve(sizeof(int) * kEtot);
  int* esrc  = (int*)carve(sizeof(int) * kEtot);
  int* epos  = (int*)carve(sizeof(int) * kEtot);
  // dead-buffer alias: MLP1 intermediate (alpha_csr dead after layer 3)
  ushort* c1h = (ushort*)alpha_csr;  // kN*128 ushorts (12.8MB) <= 27.2MB

  // ---- zero counters + conversions + Q ----
  gat_zero2<<<cdiv(kN, 256), 256, 0, stream>>>(deg, fillc, kN);
  {
    int tot = kN * 64 + 256 * 64 + 2 * 256 * 256 + 96 * 1024 + 64 * 128;
    cvt_all<<<cdiv(tot, 256), 256, 0, stream>>>(x, W[0], W[1], W[2], lw1, lw2,
                                                xh, Wt1, Wt2, Wt3, lwt1, lwt2p);
  }
  gat_make_q3<<<1, 384, 0, stream>>>(We_[0], ae_[0], We_[1], ae_[1], We_[2], ae_[2], Q3);

  // ---- CSR build + self-loop edge_attr (atomic-free) ----
  gat_count<<<cdiv(kE, 256), 256, 0, stream>>>(ei, deg);
  gat_scan_a<<<kNB, 256, 0, stream>>>(deg, offs, bsum);
  gat_scan_b<<<1, 256, 0, stream>>>(bsum, bpre);
  gat_scan_c<<<kNB, 256, 0, stream>>>(offs, bpre);
  gat_fill<<<cdiv(kEtot, 256), 256, 0, stream>>>(ei, offs, fillc, el, esrc, epos);
  gat_ealoop<<<cdiv(kN * kEd, 256), 256, 0, stream>>>(offs, el, ea, ea_loop);

  // ---- 3 GAT layers ----
  const ushort* hinh[3] = {xh, h1h, h2h};
  ushort* houth[3] = {h1h, h2h, h3h};
  const ushort* Wt[3] = {Wt1, Wt2, Wt3};
  int kdim[3] = {64, kC, kC};
  for (int l = 0; l < 3; l++) {
    dim3 ggrid(kC / 64, cdiv(kN, 64));
    gat_gemm_mfma<0, 1><<<ggrid, 256, 0, stream>>>(
        kN, kdim[l], kC, hinh[l], nullptr, nullptr, nullptr, nullptr,
        Wt[l], nullptr, nullptr, 0, xlh, kC, 0,
        as_[l], ad_[l], a_src, a_dst);
    gat_edge_alpha<<<cdiv(kEtot, 256), 256, 0, stream>>>(ei, ea, ea_loop, Q3 + l * 128,
                                                         a_src, a_dst, epos, alpha_csr);
    gat_aggregate<<<cdiv(kN, 4), 256, 0, stream>>>(offs, esrc, alpha_csr, xlh,
                                                   bb[l], houth[l]);
  }

  // ---- pooling (segmented, batch sorted) ----
  gat_pool_seg<<<kNM, kC, 0, stream>>>(h3h, batch, hpoolh);

  // ---- MLP ----
  {
    gat_zeropad<<<cdiv(kN * 4, 256), 256, 0, stream>>>(c1h);
    dim3 g1(cdiv(96, 64), cdiv(kN, 64));
    gat_gemm_mfma<2, 0><<<g1, 256, 0, stream>>>(
        kN, 4 * kC, 96, h1h, h2h, h3h, hpoolh, batch,
        lwt1, lb1, nullptr, 0, c1h, 128, 1,
        nullptr, nullptr, nullptr, nullptr);
    dim3 g2(1, cdiv(kN, 64));
    gat_gemm_mfma<0, 0><<<g2, 256, 0, stream>>>(
        kN, 128, 64, c1h, nullptr, nullptr, nullptr, nullptr,
        lwt2p, lb2, c2, 64, nullptr, 0, 1,
        nullptr, nullptr, nullptr, nullptr);
    gat_mlp3<<<cdiv(kN, 256), 256, 0, stream>>>(c2, lw3, lb3, out);
  }
}

// Round 9
// 772.251 us; speedup vs baseline: 3.7061x; 1.0773x over previous
//
#include <hip/hip_runtime.h>
#include <hip/hip_bf16.h>

namespace {
constexpr int kN    = 50000;
constexpr int kE    = 800000;
constexpr int kEtot = kE + kN;   // 850000 (self-loops appended)
constexpr int kEd   = 16;
constexpr int kH    = 8;
constexpr int kD    = 32;
constexpr int kC    = kH * kD;   // 256
constexpr int kNM   = 500;
constexpr int kNB   = (kN + 255) / 256;  // 196 scan blocks
}

typedef __attribute__((ext_vector_type(8))) _Float16 half8;
typedef __attribute__((ext_vector_type(4))) float floatx4;

__device__ __forceinline__ float h2f(ushort u) {
  union { ushort u; _Float16 h; } v;
  v.u = u;
  return (float)v.h;
}
__device__ __forceinline__ ushort f2h(float f) {
  union { _Float16 h; ushort u; } v;
  v.h = (_Float16)f;  // v_cvt_f16_f32, RNE
  return v.u;
}

// ---------------- merged small kernels ----------------
__global__ void gat_zero2(int* __restrict__ a, int* __restrict__ b, int n) {
  int i = blockIdx.x * blockDim.x + threadIdx.x;
  if (i < n) { a[i] = 0; b[i] = 0; }
}

// zero pad cols 96..127 of c1h[kN][128] (fp16)
__global__ void gat_zeropad(ushort* __restrict__ c1h) {
  int i = blockIdx.x * blockDim.x + threadIdx.x;
  if (i >= kN * 4) return;
  int row = i >> 2, q = i & 3;
  uint4 z = {0u, 0u, 0u, 0u};
  *(uint4*)(c1h + (long)row * 128 + 96 + q * 8) = z;
}

// all fp32->fp16 conversions in one launch.
__global__ void cvt_all(const float* __restrict__ x,
                        const float* __restrict__ W1, const float* __restrict__ W2,
                        const float* __restrict__ W3, const float* __restrict__ lw1,
                        const float* __restrict__ lw2,
                        ushort* __restrict__ xh, ushort* __restrict__ Wt1,
                        ushort* __restrict__ Wt2, ushort* __restrict__ Wt3,
                        ushort* __restrict__ lwt1, ushort* __restrict__ lwt2p) {
  int i = blockIdx.x * blockDim.x + threadIdx.x;
  if (i < kN * 64) { xh[i] = f2h(x[i]); return; }
  i -= kN * 64;
  if (i < 256 * 64) {  // Wt1[n][k], W1 is 64x256
    int n = i >> 6, k = i & 63;
    Wt1[i] = f2h(W1[(long)k * 256 + n]);
    return;
  }
  i -= 256 * 64;
  if (i < 256 * 256) {
    int n = i >> 8, k = i & 255;
    Wt2[i] = f2h(W2[(long)k * 256 + n]);
    return;
  }
  i -= 256 * 256;
  if (i < 256 * 256) {
    int n = i >> 8, k = i & 255;
    Wt3[i] = f2h(W3[(long)k * 256 + n]);
    return;
  }
  i -= 256 * 256;
  if (i < 96 * 1024) {  // lwt1[n][k], lw1 is 1024x96
    int n = i >> 10, k = i & 1023;
    lwt1[i] = f2h(lw1[(long)k * 96 + n]);
    return;
  }
  i -= 96 * 1024;
  if (i < 64 * 128) {  // lwt2p[n][k], K zero-padded 96->128; lw2 is 96x64
    int n = i >> 7, k = i & 127;
    lwt2p[i] = (k < 96) ? f2h(lw2[(long)k * 64 + n]) : (ushort)0;
    return;
  }
}

// Q3[l][c][h] = sum_d We_l[c, h*32+d] * ae_l[h,d]   (one launch, 384 threads)
__global__ void gat_make_q3(const float* __restrict__ We1, const float* __restrict__ ae1,
                            const float* __restrict__ We2, const float* __restrict__ ae2,
                            const float* __restrict__ We3, const float* __restrict__ ae3,
                            float* __restrict__ Q3) {
  int t = threadIdx.x;
  if (t >= 384) return;
  int l = t >> 7, r = t & 127;
  const float* We = (l == 0) ? We1 : (l == 1) ? We2 : We3;
  const float* ae = (l == 0) ? ae1 : (l == 1) ? ae2 : ae3;
  int c = r >> 3, h = r & 7;
  float s = 0.f;
#pragma unroll
  for (int d = 0; d < kD; d++) s += We[c * kC + h * kD + d] * ae[h * kD + d];
  Q3[l * 128 + c * kH + h] = s;
}

// ---------------- CSR build (shared by all 3 layers) ----------------
__global__ void gat_count(const int* __restrict__ ei, int* __restrict__ deg) {
  int e = blockIdx.x * blockDim.x + threadIdx.x;
  if (e >= kE) return;
  atomicAdd(&deg[ei[kE + e]], 1);
}

// hierarchical scan of (deg[i]+1)
__global__ __launch_bounds__(256) void gat_scan_a(const int* __restrict__ deg,
                                                  int* __restrict__ offs,
                                                  int* __restrict__ bsum) {
  __shared__ int s[256];
  int b = blockIdx.x, t = threadIdx.x;
  int i = b * 256 + t;
  int v = (i < kN) ? deg[i] + 1 : 0;
  s[t] = v;
  __syncthreads();
  for (int o = 1; o < 256; o <<= 1) {
    int u = (t >= o) ? s[t - o] : 0;
    __syncthreads();
    s[t] += u;
    __syncthreads();
  }
  if (i < kN) offs[i] = s[t] - v;
  if (t == 255) bsum[b] = s[255];
}

__global__ __launch_bounds__(256) void gat_scan_b(const int* __restrict__ bsum,
                                                  int* __restrict__ bpre) {
  __shared__ int s[256];
  int t = threadIdx.x;
  int v = (t < kNB) ? bsum[t] : 0;
  s[t] = v;
  __syncthreads();
  for (int o = 1; o < 256; o <<= 1) {
    int u = (t >= o) ? s[t - o] : 0;
    __syncthreads();
    s[t] += u;
    __syncthreads();
  }
  if (t < kNB) bpre[t] = s[t] - v;
}

__global__ void gat_scan_c(int* __restrict__ offs, const int* __restrict__ bpre) {
  int i = blockIdx.x * blockDim.x + threadIdx.x;
  if (i < kN) offs[i] += bpre[blockIdx.x];
  if (i == 0) offs[kN] = kEtot;
}

// el[pos]=edge id; esrc[pos]=src; edst[pos]=dst; epos[e]=pos
__global__ void gat_fill(const int* __restrict__ ei, const int* __restrict__ offs,
                         int* __restrict__ fillc, int* __restrict__ el,
                         int* __restrict__ esrc, int* __restrict__ edst,
                         int* __restrict__ epos) {
  int e = blockIdx.x * blockDim.x + threadIdx.x;
  if (e >= kEtot) return;
  int s, d;
  if (e < kE) { s = ei[e]; d = ei[kE + e]; }
  else { s = d = e - kE; }
  int pos = offs[d] + atomicAdd(&fillc[d], 1);
  el[pos] = e;
  esrc[pos] = s;
  edst[pos] = d;
  epos[e] = pos;
}

// ea_csr[pos][:] = ea[el[pos]][:] for real edges (streamed write, gathered read)
__global__ void gat_ea_csr(const int* __restrict__ el, const float* __restrict__ ea,
                           float* __restrict__ ea_csr) {
  int t = blockIdx.x * blockDim.x + threadIdx.x;
  if (t >= kEtot * 4) return;
  int pos = t >> 2, q = t & 3;
  int e = el[pos];
  if (e >= kE) return;  // self-loop slots filled via ea_loop path
  float4 v = *(const float4*)(ea + (long)e * kEd + q * 4);
  *(float4*)(ea_csr + (long)pos * kEd + q * 4) = v;
}

// ea_loop[n,c] = sum over real in-edges of ea (CSR-streamed reads)
__global__ void gat_ealoop(const int* __restrict__ offs, const int* __restrict__ el,
                           const float* __restrict__ ea_csr, float* __restrict__ ea_loop) {
  int t = blockIdx.x * blockDim.x + threadIdx.x;
  if (t >= kN * kEd) return;
  int n = t >> 4, c = t & 15;
  int lo = offs[n], hi = offs[n + 1];
  float s = 0.f;
  for (int j = lo; j < hi; j++) {
    if (el[j] < kE) s += ea_csr[(long)j * kEd + c];
  }
  ea_loop[t] = s;
}

// ---------------- fp16 MFMA GEMM (64M x 128N tile) ----------------
// act( A(MxK,fp16 row-major) @ Bt^T + bias ) -> C fp32 (ldc) and/or Ch fp16 (ldch)
// Bt pre-transposed [N][K] fp16.
// AMODE 0: A = A0 (row stride K).
// AMODE 2: A row r, col k: j=k>>8 -> {A0,A1,A2,A3[batch[r]]}, each row stride 256.
// COEF 1: emit a_src[row,h]=xl_row_h . as_[h], a_dst likewise (N=256; 4 heads/block).
template <int AMODE, int COEF>
__global__ __launch_bounds__(256) void gat_gemm_mfma(
    int M, int K, int N,
    const ushort* __restrict__ A0, const ushort* __restrict__ A1,
    const ushort* __restrict__ A2, const ushort* __restrict__ A3,
    const int* __restrict__ batch,
    const ushort* __restrict__ Bt, const float* __restrict__ bias,
    float* __restrict__ C, int ldc, ushort* __restrict__ Ch, int ldch, int act,
    const float* __restrict__ as_, const float* __restrict__ ad_,
    float* __restrict__ a_src, float* __restrict__ a_dst) {
  __shared__ ushort As[8][64][8];   // 8 KB
  __shared__ ushort Bs[8][128][8];  // 16 KB
  int t = threadIdx.x;
  int rowBase = blockIdx.y * 64;
  int colBase = blockIdx.x * 128;
  int w = t >> 6, L = t & 63;

  floatx4 acc[8];
#pragma unroll
  for (int i = 0; i < 8; i++) acc[i] = (floatx4){0.f, 0.f, 0.f, 0.f};

  int ar = t >> 2, akq = t & 3;  // A staging: row 0..63, k-chunk base
  int arow = rowBase + ar;
  int bn = t >> 1, bq2 = (t & 1) * 4;  // B staging: n 0..127, chunk half
  int bok = (colBase + bn) < N;
  long brow = (long)(colBase + bn) * K;

  for (int k0 = 0; k0 < K; k0 += 64) {
    // ---- stage A (2 chunks/thread) ----
#pragma unroll
    for (int half = 0; half < 2; half++) {
      int q = akq + half * 4;
      int gk = k0 + q * 8;
      uint4 av = {0u, 0u, 0u, 0u};
      if (arow < M) {
        if (AMODE == 0) {
          av = *(const uint4*)(A0 + (long)arow * K + gk);
        } else {
          int j = gk >> 8, kc = gk & 255;
          const ushort* src = (j == 0) ? A0 : (j == 1) ? A1 : (j == 2) ? A2 : A3;
          long rr = (j == 3) ? (long)batch[arow] : (long)arow;
          av = *(const uint4*)(src + rr * 256 + kc);
        }
      }
      *(uint4*)&As[q][ar][0] = av;
    }
    // ---- stage B (4 chunks/thread) ----
#pragma unroll
    for (int u = 0; u < 4; u++) {
      int q = bq2 + u;
      uint4 bv = {0u, 0u, 0u, 0u};
      if (bok) bv = *(const uint4*)(Bt + brow + k0 + q * 8);
      *(uint4*)&Bs[q][bn][0] = bv;
    }
    __syncthreads();
    int mrow = w * 16 + (L & 15);
    int nl = L & 15;
#pragma unroll
    for (int half = 0; half < 2; half++) {
      int q = (L >> 4) + half * 4;
      half8 af = *(const half8*)&As[q][mrow][0];
#pragma unroll
      for (int t8 = 0; t8 < 8; t8++) {
        half8 bf = *(const half8*)&Bs[q][t8 * 16 + nl][0];
        acc[t8] = __builtin_amdgcn_mfma_f32_16x16x32_f16(af, bf, acc[t8], 0, 0, 0);
      }
    }
    __syncthreads();
  }
  // ---- epilogue: C/D layout col=lane&15, row=(lane>>4)*4+reg ----
  int nlo = L & 15;
  int rbase = rowBase + w * 16 + (L >> 4) * 4;
#pragma unroll
  for (int t8 = 0; t8 < 8; t8++) {
    int col = colBase + t8 * 16 + nlo;
    if (col >= N) continue;
    float bv = bias ? bias[col] : 0.f;
#pragma unroll
    for (int r = 0; r < 4; r++) {
      int row = rbase + r;
      if (row >= M) continue;
      float v = acc[t8][r] + bv;
      if (act == 1) v = v > 0.f ? v : 0.01f * v;
      if (C) C[(long)row * ldc + col] = v;
      if (Ch) Ch[(long)row * ldch + col] = f2h(v);
    }
  }
  if (COEF) {
    // 4 heads per block: hA = colBase>>5 .. +3; head g = t8>>1, widx=(t8&1)*16+nlo
    float ps[4][4], pd[4][4];
#pragma unroll
    for (int g = 0; g < 4; g++)
#pragma unroll
      for (int r = 0; r < 4; r++) { ps[g][r] = 0.f; pd[g][r] = 0.f; }
    int hA = colBase >> 5;
#pragma unroll
    for (int t8 = 0; t8 < 8; t8++) {
      int g = t8 >> 1;
      int widx = (t8 & 1) * 16 + nlo;
      float wsv = as_[(hA + g) * kD + widx];
      float wdv = ad_[(hA + g) * kD + widx];
#pragma unroll
      for (int r = 0; r < 4; r++) {
        ps[g][r] += acc[t8][r] * wsv;
        pd[g][r] += acc[t8][r] * wdv;
      }
    }
#pragma unroll
    for (int m = 1; m < 16; m <<= 1) {
#pragma unroll
      for (int g = 0; g < 4; g++)
#pragma unroll
        for (int r = 0; r < 4; r++) {
          ps[g][r] += __shfl_xor(ps[g][r], m);
          pd[g][r] += __shfl_xor(pd[g][r], m);
        }
    }
    if (nlo == 0) {
#pragma unroll
      for (int r = 0; r < 4; r++) {
        int row = rbase + r;
        if (row >= M) continue;
#pragma unroll
        for (int g = 0; g < 4; g++) {
          a_src[row * kH + hA + g] = ps[g][r];
          a_dst[row * kH + hA + g] = pd[g][r];
        }
      }
    }
  }
}

// ---------------- per-layer small kernels ----------------
// pos-ordered: alpha_csr[pos*8+h] = leakyrelu( a_src[esrc[pos],h] + a_dst[edst[pos],h]
//                                              + ea_csr[pos] . Q[:,h] )   (all streams)
__global__ void gat_edge_alpha(const int* __restrict__ el, const int* __restrict__ esrc,
                               const int* __restrict__ edst,
                               const float* __restrict__ ea_csr,
                               const float* __restrict__ ea_loop, const float* __restrict__ Q,
                               const float* __restrict__ a_src, const float* __restrict__ a_dst,
                               float* __restrict__ alpha_csr) {
  int pos = blockIdx.x * blockDim.x + threadIdx.x;
  if (pos >= kEtot) return;
  int e = el[pos];
  int s = esrc[pos];
  int d = edst[pos];
  const float* row = (e < kE) ? (ea_csr + (long)pos * kEd) : (ea_loop + (long)d * kEd);
  float eav[kEd];
#pragma unroll
  for (int q = 0; q < kEd / 4; q++) {
    float4 v = *(const float4*)(row + q * 4);
    eav[q * 4 + 0] = v.x; eav[q * 4 + 1] = v.y;
    eav[q * 4 + 2] = v.z; eav[q * 4 + 3] = v.w;
  }
  const float* asr = a_src + s * kH;
  const float* adr = a_dst + d * kH;
  float av[kH];
#pragma unroll
  for (int h = 0; h < kH; h++) {
    float q = 0.f;
#pragma unroll
    for (int c = 0; c < kEd; c++) q += eav[c] * Q[c * kH + h];
    float a = asr[h] + adr[h] + q;
    av[h] = a > 0.f ? a : 0.2f * a;
  }
  long base = (long)pos * kH;
  *(float4*)(alpha_csr + base) = make_float4(av[0], av[1], av[2], av[3]);
  *(float4*)(alpha_csr + base + 4) = make_float4(av[4], av[5], av[6], av[7]);
}

// one wave per node; fused segment-softmax + aggregation.
__global__ __launch_bounds__(256) void gat_aggregate(
    const int* __restrict__ offs, const int* __restrict__ esrc,
    const float* __restrict__ alpha_csr,
    const ushort* __restrict__ xlh, const float* __restrict__ bias,
    ushort* __restrict__ hh) {
  int n = blockIdx.x * 4 + (threadIdx.x >> 6);
  if (n >= kN) return;
  int L = threadIdx.x & 63;
  int lo = offs[n], hi = offs[n + 1];
  // ---- fused per-head (max, sum): lane = (slice L>>3, head L&7) ----
  int hp = L & 7, sl = L >> 3;
  float m = -1e30f, s = 0.f;
  for (int j = lo + sl; j < hi; j += 8) {
    float a = alpha_csr[(long)j * kH + hp];
    if (a > m) { s = s * __expf(m - a) + 1.f; m = a; }
    else s += __expf(a - m);
  }
#pragma unroll
  for (int msk = 8; msk < 64; msk <<= 1) {
    float om = __shfl_xor(m, msk);
    float os = __shfl_xor(s, msk);
    float nm = fmaxf(m, om);
    s = s * __expf(m - nm) + os * __expf(om - nm);
    m = nm;
  }
  int eh = L >> 5;        // which edge of the pair
  int cl = L & 31;
  int c = cl * 8;         // 8 channels per lane
  int h = cl >> 2;
  float mh = __shfl(m, h);
  float invs = 1.f / __shfl(s, h);
  float acc[8] = {0.f, 0.f, 0.f, 0.f, 0.f, 0.f, 0.f, 0.f};
  union { uint4 u; _Float16 hf[8]; } v0, v1;
  int j = lo;
  // guard-free main loop: 4 edges per wave-iter, 2 independent chains per lane
  for (; j + 4 <= hi; j += 4) {
    int jj0 = j + eh, jj1 = j + 2 + eh;
    int s0 = esrc[jj0], s1 = esrc[jj1];
    float t0 = __expf(alpha_csr[(long)jj0 * kH + h] - mh) * invs;
    float t1 = __expf(alpha_csr[(long)jj1 * kH + h] - mh) * invs;
    v0.u = *(const uint4*)(xlh + (long)s0 * kC + c);
    v1.u = *(const uint4*)(xlh + (long)s1 * kC + c);
#pragma unroll
    for (int i = 0; i < 8; i++) acc[i] += t0 * (float)v0.hf[i];
#pragma unroll
    for (int i = 0; i < 8; i++) acc[i] += t1 * (float)v1.hf[i];
  }
  for (; j < hi; j += 2) {
    int jj = j + eh;
    bool valid = jj < hi;
    int js = valid ? jj : lo;
    int sn = esrc[js];
    float att = valid ? __expf(alpha_csr[(long)jj * kH + h] - mh) * invs : 0.f;
    v0.u = *(const uint4*)(xlh + (long)sn * kC + c);
#pragma unroll
    for (int i = 0; i < 8; i++) acc[i] += att * (float)v0.hf[i];
  }
#pragma unroll
  for (int i = 0; i < 8; i++) acc[i] += __shfl_xor(acc[i], 32);
  if (eh == 0) {
    float4 b0 = *(const float4*)(bias + c);
    float4 b1 = *(const float4*)(bias + c + 4);
    ushort o[8];
    o[0] = f2h(acc[0] + b0.x); o[1] = f2h(acc[1] + b0.y);
    o[2] = f2h(acc[2] + b0.z); o[3] = f2h(acc[3] + b0.w);
    o[4] = f2h(acc[4] + b1.x); o[5] = f2h(acc[5] + b1.y);
    o[6] = f2h(acc[6] + b1.z); o[7] = f2h(acc[7] + b1.w);
    *(uint4*)(hh + (long)n * kC + c) = *(uint4*)o;
  }
}

// ---------------- pooling (batch sorted -> segmented reduce) ----------------
__global__ __launch_bounds__(256) void gat_pool_seg(const ushort* __restrict__ h3h,
                                                    const int* __restrict__ batch,
                                                    ushort* __restrict__ hpoolh) {
  int m = blockIdx.x;
  int c = threadIdx.x;
  int lo = 0, hi = kN;
  while (lo < hi) { int mid = (lo + hi) >> 1; if (batch[mid] < m) lo = mid + 1; else hi = mid; }
  int start = lo;
  hi = kN;
  while (lo < hi) { int mid = (lo + hi) >> 1; if (batch[mid] < m + 1) lo = mid + 1; else hi = mid; }
  int end = lo;
  float s = 0.f;
  for (int n = start; n < end; n++) s += h2f(h3h[(long)n * kC + c]);
  hpoolh[(long)m * kC + c] = f2h(s);
}

__global__ void gat_mlp3(const float* __restrict__ c2, const float* __restrict__ lw3,
                         const float* __restrict__ lb3, float* __restrict__ out) {
  int n = blockIdx.x * blockDim.x + threadIdx.x;
  if (n >= kN) return;
  float s = lb3[0];
  const float* r = c2 + (long)n * 64;
#pragma unroll
  for (int k = 0; k < 64; k++) s += r[k] * lw3[k];
  float v = 1.f / (1.f + __expf(-s));
  out[n] = v;
}

// ---------------- host ----------------
static inline int cdiv(int a, int b) { return (a + b - 1) / b; }

extern "C" void kernel_launch(void* const* d_in, const int* in_sizes, int n_in,
                              void* d_out, int out_size, void* d_ws, size_t ws_size,
                              hipStream_t stream) {
  (void)in_sizes; (void)n_in; (void)out_size; (void)ws_size;
  const float* x = (const float*)d_in[0];
  const int* ei = (const int*)d_in[1];
  const float* ea = (const float*)d_in[2];
  const int* batch = (const int*)d_in[3];
  const float *W[3], *as_[3], *ad_[3], *We_[3], *ae_[3], *bb[3];
  for (int l = 0; l < 3; l++) {
    W[l]   = (const float*)d_in[4 + 6 * l];
    as_[l] = (const float*)d_in[5 + 6 * l];
    ad_[l] = (const float*)d_in[6 + 6 * l];
    We_[l] = (const float*)d_in[7 + 6 * l];
    ae_[l] = (const float*)d_in[8 + 6 * l];
    bb[l]  = (const float*)d_in[9 + 6 * l];
  }
  const float* lw1 = (const float*)d_in[22];
  const float* lb1 = (const float*)d_in[23];
  const float* lw2 = (const float*)d_in[24];
  const float* lb2 = (const float*)d_in[25];
  const float* lw3 = (const float*)d_in[26];
  const float* lb3 = (const float*)d_in[27];
  float* out = (float*)d_out;

  char* p = (char*)d_ws;
  auto carve = [&](size_t bytes) -> void* {
    void* r = (void*)p;
    p += (bytes + 255) & ~(size_t)255;
    return r;
  };
  float* alpha_csr = (float*)carve(sizeof(float) * (size_t)kEtot * kH);
  float* ea_csr  = (float*)carve(sizeof(float) * (size_t)kEtot * kEd);
  float* a_src   = (float*)carve(sizeof(float) * (size_t)kN * kH);
  float* a_dst   = (float*)carve(sizeof(float) * (size_t)kN * kH);
  float* ea_loop = (float*)carve(sizeof(float) * (size_t)kN * kEd);
  float* Q3      = (float*)carve(sizeof(float) * 3 * 128);
  float* c2      = (float*)carve(sizeof(float) * (size_t)kN * 64);
  ushort* xh     = (ushort*)carve(sizeof(ushort) * (size_t)kN * 64);
  ushort* xlh    = (ushort*)carve(sizeof(ushort) * (size_t)kN * kC);
  ushort* h1h    = (ushort*)carve(sizeof(ushort) * (size_t)kN * kC);
  ushort* h2h    = (ushort*)carve(sizeof(ushort) * (size_t)kN * kC);
  ushort* h3h    = (ushort*)carve(sizeof(ushort) * (size_t)kN * kC);
  ushort* hpoolh = (ushort*)carve(sizeof(ushort) * (size_t)kNM * kC);
  ushort* Wt1    = (ushort*)carve(sizeof(ushort) * 64 * 256);
  ushort* Wt2    = (ushort*)carve(sizeof(ushort) * 256 * 256);
  ushort* Wt3    = (ushort*)carve(sizeof(ushort) * 256 * 256);
  ushort* lwt1   = (ushort*)carve(sizeof(ushort) * 1024 * 96);
  ushort* lwt2p  = (ushort*)carve(sizeof(ushort) * 64 * 128);
  int* deg   = (int*)carve(sizeof(int) * kN);
  int* fillc = (int*)carve(sizeof(int) * kN);
  int* offs  = (int*)carve(sizeof(int) * (kN + 1));
  int* bsum  = (int*)carve(sizeof(int) * 256);
  int* bpre  = (int*)carve(sizeof(int) * 256);
  int* el    = (int*)carve(sizeof(int) * kEtot);
  int* esrc  = (int*)carve(sizeof(int) * kEtot);
  int* edst  = (int*)carve(sizeof(int) * kEtot);
  int* epos  = (int*)carve(sizeof(int) * kEtot);
  // dead-buffer alias: MLP1 intermediate (alpha_csr dead after layer 3)
  ushort* c1h = (ushort*)alpha_csr;  // kN*128 ushorts (12.8MB) <= 27.2MB

  // ---- zero counters + conversions + Q ----
  gat_zero2<<<cdiv(kN, 256), 256, 0, stream>>>(deg, fillc, kN);
  {
    int tot = kN * 64 + 256 * 64 + 2 * 256 * 256 + 96 * 1024 + 64 * 128;
    cvt_all<<<cdiv(tot, 256), 256, 0, stream>>>(x, W[0], W[1], W[2], lw1, lw2,
                                                xh, Wt1, Wt2, Wt3, lwt1, lwt2p);
  }
  gat_make_q3<<<1, 384, 0, stream>>>(We_[0], ae_[0], We_[1], ae_[1], We_[2], ae_[2], Q3);

  // ---- CSR build + ea permute + self-loop edge_attr ----
  gat_count<<<cdiv(kE, 256), 256, 0, stream>>>(ei, deg);
  gat_scan_a<<<kNB, 256, 0, stream>>>(deg, offs, bsum);
  gat_scan_b<<<1, 256, 0, stream>>>(bsum, bpre);
  gat_scan_c<<<kNB, 256, 0, stream>>>(offs, bpre);
  gat_fill<<<cdiv(kEtot, 256), 256, 0, stream>>>(ei, offs, fillc, el, esrc, edst, epos);
  gat_ea_csr<<<cdiv(kEtot * 4, 256), 256, 0, stream>>>(el, ea, ea_csr);
  gat_ealoop<<<cdiv(kN * kEd, 256), 256, 0, stream>>>(offs, el, ea_csr, ea_loop);

  // ---- 3 GAT layers ----
  const ushort* hinh[3] = {xh, h1h, h2h};
  ushort* houth[3] = {h1h, h2h, h3h};
  const ushort* Wt[3] = {Wt1, Wt2, Wt3};
  int kdim[3] = {64, kC, kC};
  for (int l = 0; l < 3; l++) {
    dim3 ggrid(kC / 128, cdiv(kN, 64));
    gat_gemm_mfma<0, 1><<<ggrid, 256, 0, stream>>>(
        kN, kdim[l], kC, hinh[l], nullptr, nullptr, nullptr, nullptr,
        Wt[l], nullptr, nullptr, 0, xlh, kC, 0,
        as_[l], ad_[l], a_src, a_dst);
    gat_edge_alpha<<<cdiv(kEtot, 256), 256, 0, stream>>>(el, esrc, edst, ea_csr, ea_loop,
                                                         Q3 + l * 128, a_src, a_dst, alpha_csr);
    gat_aggregate<<<cdiv(kN, 4), 256, 0, stream>>>(offs, esrc, alpha_csr, xlh,
                                                   bb[l], houth[l]);
  }

  // ---- pooling (segmented, batch sorted) ----
  gat_pool_seg<<<kNM, kC, 0, stream>>>(h3h, batch, hpoolh);

  // ---- MLP ----
  {
    gat_zeropad<<<cdiv(kN * 4, 256), 256, 0, stream>>>(c1h);
    dim3 g1(1, cdiv(kN, 64));
    gat_gemm_mfma<2, 0><<<g1, 256, 0, stream>>>(
        kN, 4 * kC, 96, h1h, h2h, h3h, hpoolh, batch,
        lwt1, lb1, nullptr, 0, c1h, 128, 1,
        nullptr, nullptr, nullptr, nullptr);
    dim3 g2(1, cdiv(kN, 64));
    gat_gemm_mfma<0, 0><<<g2, 256, 0, stream>>>(
        kN, 128, 64, c1h, nullptr, nullptr, nullptr, nullptr,
        lwt2p, lb2, c2, 64, nullptr, 0, 1,
        nullptr, nullptr, nullptr, nullptr);
    gat_mlp3<<<cdiv(kN, 256), 256, 0, stream>>>(c2, lw3, lb3, out);
  }
}

// Round 11
// 737.940 us; speedup vs baseline: 3.8784x; 1.0465x over previous
//
#include <hip/hip_runtime.h>
#include <hip/hip_bf16.h>

namespace {
constexpr int kN    = 50000;
constexpr int kE    = 800000;
constexpr int kEtot = kE + kN;   // 850000 (self-loops appended)
constexpr int kEd   = 16;
constexpr int kH    = 8;
constexpr int kD    = 32;
constexpr int kC    = kH * kD;   // 256
constexpr int kNM   = 500;
constexpr int kNB   = (kN + 255) / 256;  // 196 scan blocks
constexpr int kCap  = 128;               // LDS softmax capacity (max deg ~45 here)
}

typedef __attribute__((ext_vector_type(8))) _Float16 half8;
typedef __attribute__((ext_vector_type(4))) float floatx4;

__device__ __forceinline__ float h2f(ushort u) {
  union { ushort u; _Float16 h; } v;
  v.u = u;
  return (float)v.h;
}
__device__ __forceinline__ ushort f2h(float f) {
  union { _Float16 h; ushort u; } v;
  v.h = (_Float16)f;  // v_cvt_f16_f32, RNE
  return v.u;
}

// ---------------- merged small kernels ----------------
__global__ void gat_zero2(int* __restrict__ a, int* __restrict__ b, int n) {
  int i = blockIdx.x * blockDim.x + threadIdx.x;
  if (i < n) { a[i] = 0; b[i] = 0; }
}

// zero pad cols 96..127 of c1h[kN][128] (fp16)
__global__ void gat_zeropad(ushort* __restrict__ c1h) {
  int i = blockIdx.x * blockDim.x + threadIdx.x;
  if (i >= kN * 4) return;
  int row = i >> 2, q = i & 3;
  uint4 z = {0u, 0u, 0u, 0u};
  *(uint4*)(c1h + (long)row * 128 + 96 + q * 8) = z;
}

// all fp32->fp16 conversions in one launch.
__global__ void cvt_all(const float* __restrict__ x,
                        const float* __restrict__ W1, const float* __restrict__ W2,
                        const float* __restrict__ W3, const float* __restrict__ lw1,
                        const float* __restrict__ lw2,
                        ushort* __restrict__ xh, ushort* __restrict__ Wt1,
                        ushort* __restrict__ Wt2, ushort* __restrict__ Wt3,
                        ushort* __restrict__ lwt1, ushort* __restrict__ lwt2p) {
  int i = blockIdx.x * blockDim.x + threadIdx.x;
  if (i < kN * 64) { xh[i] = f2h(x[i]); return; }
  i -= kN * 64;
  if (i < 256 * 64) {  // Wt1[n][k], W1 is 64x256
    int n = i >> 6, k = i & 63;
    Wt1[i] = f2h(W1[(long)k * 256 + n]);
    return;
  }
  i -= 256 * 64;
  if (i < 256 * 256) {
    int n = i >> 8, k = i & 255;
    Wt2[i] = f2h(W2[(long)k * 256 + n]);
    return;
  }
  i -= 256 * 256;
  if (i < 256 * 256) {
    int n = i >> 8, k = i & 255;
    Wt3[i] = f2h(W3[(long)k * 256 + n]);
    return;
  }
  i -= 256 * 256;
  if (i < 96 * 1024) {  // lwt1[n][k], lw1 is 1024x96
    int n = i >> 10, k = i & 1023;
    lwt1[i] = f2h(lw1[(long)k * 96 + n]);
    return;
  }
  i -= 96 * 1024;
  if (i < 64 * 128) {  // lwt2p[n][k], K zero-padded 96->128; lw2 is 96x64
    int n = i >> 7, k = i & 127;
    lwt2p[i] = (k < 96) ? f2h(lw2[(long)k * 64 + n]) : (ushort)0;
    return;
  }
}

// Q3[l][c][h] = sum_d We_l[c, h*32+d] * ae_l[h,d]   (one launch, 384 threads)
__global__ void gat_make_q3(const float* __restrict__ We1, const float* __restrict__ ae1,
                            const float* __restrict__ We2, const float* __restrict__ ae2,
                            const float* __restrict__ We3, const float* __restrict__ ae3,
                            float* __restrict__ Q3) {
  int t = threadIdx.x;
  if (t >= 384) return;
  int l = t >> 7, r = t & 127;
  const float* We = (l == 0) ? We1 : (l == 1) ? We2 : We3;
  const float* ae = (l == 0) ? ae1 : (l == 1) ? ae2 : ae3;
  int c = r >> 3, h = r & 7;
  float s = 0.f;
#pragma unroll
  for (int d = 0; d < kD; d++) s += We[c * kC + h * kD + d] * ae[h * kD + d];
  Q3[l * 128 + c * kH + h] = s;
}

// ---------------- CSR build (shared by all 3 layers) ----------------
__global__ void gat_count(const int* __restrict__ ei, int* __restrict__ deg) {
  int e = blockIdx.x * blockDim.x + threadIdx.x;
  if (e >= kE) return;
  atomicAdd(&deg[ei[kE + e]], 1);
}

// hierarchical scan of (deg[i]+1)
__global__ __launch_bounds__(256) void gat_scan_a(const int* __restrict__ deg,
                                                  int* __restrict__ offs,
                                                  int* __restrict__ bsum) {
  __shared__ int s[256];
  int b = blockIdx.x, t = threadIdx.x;
  int i = b * 256 + t;
  int v = (i < kN) ? deg[i] + 1 : 0;
  s[t] = v;
  __syncthreads();
  for (int o = 1; o < 256; o <<= 1) {
    int u = (t >= o) ? s[t - o] : 0;
    __syncthreads();
    s[t] += u;
    __syncthreads();
  }
  if (i < kN) offs[i] = s[t] - v;
  if (t == 255) bsum[b] = s[255];
}

__global__ __launch_bounds__(256) void gat_scan_b(const int* __restrict__ bsum,
                                                  int* __restrict__ bpre) {
  __shared__ int s[256];
  int t = threadIdx.x;
  int v = (t < kNB) ? bsum[t] : 0;
  s[t] = v;
  __syncthreads();
  for (int o = 1; o < 256; o <<= 1) {
    int u = (t >= o) ? s[t - o] : 0;
    __syncthreads();
    s[t] += u;
    __syncthreads();
  }
  if (t < kNB) bpre[t] = s[t] - v;
}

__global__ void gat_scan_c(int* __restrict__ offs, const int* __restrict__ bpre) {
  int i = blockIdx.x * blockDim.x + threadIdx.x;
  if (i < kN) offs[i] += bpre[blockIdx.x];
  if (i == 0) offs[kN] = kEtot;
}

// el[pos]=edge id; esrc[pos]=src; epos[e]=pos
__global__ void gat_fill(const int* __restrict__ ei, const int* __restrict__ offs,
                         int* __restrict__ fillc, int* __restrict__ el,
                         int* __restrict__ esrc, int* __restrict__ epos) {
  int e = blockIdx.x * blockDim.x + threadIdx.x;
  if (e >= kEtot) return;
  int s, d;
  if (e < kE) { s = ei[e]; d = ei[kE + e]; }
  else { s = d = e - kE; }
  int pos = offs[d] + atomicAdd(&fillc[d], 1);
  el[pos] = e;
  esrc[pos] = s;
  epos[e] = pos;
}

// aqX[pos*8+h] = ea[el[pos]] . Q_l[:,h]  for l=0..2 (CSR-ordered planes).
// Self-loop slots get 0 (gat_aqsum fills them with the segment sum -- linearity of the dot).
__global__ __launch_bounds__(256) void gat_aq(const int* __restrict__ el,
                                              const float* __restrict__ ea,
                                              const float* __restrict__ Q3,
                                              float* __restrict__ aq0,
                                              float* __restrict__ aq1,
                                              float* __restrict__ aq2) {
  __shared__ float Qs[384];
  int t = threadIdx.x;
  for (int i = t; i < 384; i += 256) Qs[i] = Q3[i];  // FIX: 384 entries, 256 threads
  __syncthreads();
  int pos = blockIdx.x * blockDim.x + t;
  if (pos >= kEtot) return;
  int e = el[pos];
  long base = (long)pos * kH;
  if (e >= kE) {
    float4 z = make_float4(0.f, 0.f, 0.f, 0.f);
    *(float4*)(aq0 + base) = z; *(float4*)(aq0 + base + 4) = z;
    *(float4*)(aq1 + base) = z; *(float4*)(aq1 + base + 4) = z;
    *(float4*)(aq2 + base) = z; *(float4*)(aq2 + base + 4) = z;
    return;
  }
  float eav[kEd];
#pragma unroll
  for (int q = 0; q < kEd / 4; q++) {
    float4 v = *(const float4*)(ea + (long)e * kEd + q * 4);
    eav[q * 4 + 0] = v.x; eav[q * 4 + 1] = v.y;
    eav[q * 4 + 2] = v.z; eav[q * 4 + 3] = v.w;
  }
  float* outp[3] = {aq0, aq1, aq2};
#pragma unroll
  for (int l = 0; l < 3; l++) {
    float av[kH];
#pragma unroll
    for (int h = 0; h < kH; h++) {
      float q = 0.f;
#pragma unroll
      for (int c = 0; c < kEd; c++) q += eav[c] * Qs[l * 128 + c * kH + h];
      av[h] = q;
    }
    *(float4*)(outp[l] + base) = make_float4(av[0], av[1], av[2], av[3]);
    *(float4*)(outp[l] + base + 4) = make_float4(av[4], av[5], av[6], av[7]);
  }
}

// self-loop slot <- segment sum of aq (self slot holds 0, so summing all j is exact)
__global__ void gat_aqsum(const int* __restrict__ offs, const int* __restrict__ epos,
                          float* __restrict__ aq0, float* __restrict__ aq1,
                          float* __restrict__ aq2) {
  int t = blockIdx.x * blockDim.x + threadIdx.x;
  if (t >= kN * kH) return;
  int n = t >> 3, h = t & 7;
  int lo = offs[n], hi = offs[n + 1];
  float s0 = 0.f, s1 = 0.f, s2 = 0.f;
  for (int j = lo; j < hi; j++) {
    s0 += aq0[(long)j * kH + h];
    s1 += aq1[(long)j * kH + h];
    s2 += aq2[(long)j * kH + h];
  }
  long sp = (long)epos[kE + n] * kH + h;
  aq0[sp] = s0;
  aq1[sp] = s1;
  aq2[sp] = s2;
}

// ---------------- fp16 MFMA GEMM (64M x 128N tile) ----------------
// act( A(MxK,fp16 row-major) @ Bt^T + bias ) -> C fp32 (ldc) and/or Ch fp16 (ldch)
// AMODE 0: A = A0.  AMODE 2: A = concat[A0,A1,A2,A3[batch]] row stride 256.
// COEF 1: emit a_src[row,h]=xl_row_h . as_[h], a_dst likewise (N=256; 4 heads/block).
template <int AMODE, int COEF>
__global__ __launch_bounds__(256) void gat_gemm_mfma(
    int M, int K, int N,
    const ushort* __restrict__ A0, const ushort* __restrict__ A1,
    const ushort* __restrict__ A2, const ushort* __restrict__ A3,
    const int* __restrict__ batch,
    const ushort* __restrict__ Bt, const float* __restrict__ bias,
    float* __restrict__ C, int ldc, ushort* __restrict__ Ch, int ldch, int act,
    const float* __restrict__ as_, const float* __restrict__ ad_,
    float* __restrict__ a_src, float* __restrict__ a_dst) {
  __shared__ ushort As[8][64][8];   // 8 KB
  __shared__ ushort Bs[8][128][8];  // 16 KB
  int t = threadIdx.x;
  int rowBase = blockIdx.y * 64;
  int colBase = blockIdx.x * 128;
  int w = t >> 6, L = t & 63;

  floatx4 acc[8];
#pragma unroll
  for (int i = 0; i < 8; i++) acc[i] = (floatx4){0.f, 0.f, 0.f, 0.f};

  int ar = t >> 2, akq = t & 3;  // A staging: row 0..63, k-chunk base
  int arow = rowBase + ar;
  int bn = t >> 1, bq2 = (t & 1) * 4;  // B staging: n 0..127, chunk half
  int bok = (colBase + bn) < N;
  long brow = (long)(colBase + bn) * K;

  for (int k0 = 0; k0 < K; k0 += 64) {
#pragma unroll
    for (int half = 0; half < 2; half++) {
      int q = akq + half * 4;
      int gk = k0 + q * 8;
      uint4 av = {0u, 0u, 0u, 0u};
      if (arow < M) {
        if (AMODE == 0) {
          av = *(const uint4*)(A0 + (long)arow * K + gk);
        } else {
          int j = gk >> 8, kc = gk & 255;
          const ushort* src = (j == 0) ? A0 : (j == 1) ? A1 : (j == 2) ? A2 : A3;
          long rr = (j == 3) ? (long)batch[arow] : (long)arow;
          av = *(const uint4*)(src + rr * 256 + kc);
        }
      }
      *(uint4*)&As[q][ar][0] = av;
    }
#pragma unroll
    for (int u = 0; u < 4; u++) {
      int q = bq2 + u;
      uint4 bv = {0u, 0u, 0u, 0u};
      if (bok) bv = *(const uint4*)(Bt + brow + k0 + q * 8);
      *(uint4*)&Bs[q][bn][0] = bv;
    }
    __syncthreads();
    int mrow = w * 16 + (L & 15);
    int nl = L & 15;
#pragma unroll
    for (int half = 0; half < 2; half++) {
      int q = (L >> 4) + half * 4;
      half8 af = *(const half8*)&As[q][mrow][0];
#pragma unroll
      for (int t8 = 0; t8 < 8; t8++) {
        half8 bf = *(const half8*)&Bs[q][t8 * 16 + nl][0];
        acc[t8] = __builtin_amdgcn_mfma_f32_16x16x32_f16(af, bf, acc[t8], 0, 0, 0);
      }
    }
    __syncthreads();
  }
  int nlo = L & 15;
  int rbase = rowBase + w * 16 + (L >> 4) * 4;
#pragma unroll
  for (int t8 = 0; t8 < 8; t8++) {
    int col = colBase + t8 * 16 + nlo;
    if (col >= N) continue;
    float bv = bias ? bias[col] : 0.f;
#pragma unroll
    for (int r = 0; r < 4; r++) {
      int row = rbase + r;
      if (row >= M) continue;
      float v = acc[t8][r] + bv;
      if (act == 1) v = v > 0.f ? v : 0.01f * v;
      if (C) C[(long)row * ldc + col] = v;
      if (Ch) Ch[(long)row * ldch + col] = f2h(v);
    }
  }
  if (COEF) {
    float ps[4][4], pd[4][4];
#pragma unroll
    for (int g = 0; g < 4; g++)
#pragma unroll
      for (int r = 0; r < 4; r++) { ps[g][r] = 0.f; pd[g][r] = 0.f; }
    int hA = colBase >> 5;
#pragma unroll
    for (int t8 = 0; t8 < 8; t8++) {
      int g = t8 >> 1;
      int widx = (t8 & 1) * 16 + nlo;
      float wsv = as_[(hA + g) * kD + widx];
      float wdv = ad_[(hA + g) * kD + widx];
#pragma unroll
      for (int r = 0; r < 4; r++) {
        ps[g][r] += acc[t8][r] * wsv;
        pd[g][r] += acc[t8][r] * wdv;
      }
    }
#pragma unroll
    for (int m = 1; m < 16; m <<= 1) {
#pragma unroll
      for (int g = 0; g < 4; g++)
#pragma unroll
        for (int r = 0; r < 4; r++) {
          ps[g][r] += __shfl_xor(ps[g][r], m);
          pd[g][r] += __shfl_xor(pd[g][r], m);
        }
    }
    if (nlo == 0) {
#pragma unroll
      for (int r = 0; r < 4; r++) {
        int row = rbase + r;
        if (row >= M) continue;
#pragma unroll
        for (int g = 0; g < 4; g++) {
          a_src[row * kH + hA + g] = ps[g][r];
          a_dst[row * kH + hA + g] = pd[g][r];
        }
      }
    }
  }
}

// ---------------- fused logits + segment-softmax + aggregation ----------------
// one wave per node. Logit a = leaky(a_src[src,h] + a_dst[n,h] + aq[pos,h]).
// LDS-staged p=exp(a-m) (deg<=kCap); one exp per (edge,head); 1/s applied in epilogue.
__global__ __launch_bounds__(256) void gat_aggregate(
    const int* __restrict__ offs, const int* __restrict__ esrc,
    const float* __restrict__ aq,
    const float* __restrict__ a_src, const float* __restrict__ a_dst,
    const ushort* __restrict__ xlh, const float* __restrict__ bias,
    ushort* __restrict__ hh) {
  __shared__ float alf[4][kCap][kH];  // 16 KB
  int wid = threadIdx.x >> 6;
  int n = blockIdx.x * 4 + wid;  // grid is exact: kN % 4 == 0
  int L = threadIdx.x & 63;
  int lo = offs[n], hi = offs[n + 1];
  int deg = hi - lo;
  bool fits = (deg <= kCap);
  int hp = L & 7, sl = L >> 3;
  float adr = a_dst[n * kH + hp];
  float m = -1e30f;
  if (fits) {
    for (int j = lo + sl; j < hi; j += 8) {
      float a = a_src[esrc[j] * kH + hp] + adr + aq[(long)j * kH + hp];
      a = a > 0.f ? a : 0.2f * a;
      alf[wid][j - lo][hp] = a;
      m = fmaxf(m, a);
    }
  } else {
    for (int j = lo + sl; j < hi; j += 8) {
      float a = a_src[esrc[j] * kH + hp] + adr + aq[(long)j * kH + hp];
      a = a > 0.f ? a : 0.2f * a;
      m = fmaxf(m, a);
    }
  }
#pragma unroll
  for (int msk = 8; msk < 64; msk <<= 1) m = fmaxf(m, __shfl_xor(m, msk));
  __syncthreads();
  float s = 0.f;
  if (fits) {
    for (int j = lo + sl; j < hi; j += 8) {
      float pp = __expf(alf[wid][j - lo][hp] - m);
      alf[wid][j - lo][hp] = pp;
      s += pp;
    }
  } else {
    for (int j = lo + sl; j < hi; j += 8) {
      float a = a_src[esrc[j] * kH + hp] + adr + aq[(long)j * kH + hp];
      a = a > 0.f ? a : 0.2f * a;
      s += __expf(a - m);
    }
  }
#pragma unroll
  for (int msk = 8; msk < 64; msk <<= 1) s += __shfl_xor(s, msk);
  __syncthreads();
  // ---- main: half-wave per edge, 2 edges x 2 chains per iter ----
  int eh = L >> 5;
  int cl = L & 31;
  int c = cl * 8;
  int h = cl >> 2;
  float invs = 1.f / __shfl(s, h);
  float mh = __shfl(m, h);
  float acc[8] = {0.f, 0.f, 0.f, 0.f, 0.f, 0.f, 0.f, 0.f};
  union { uint4 u; _Float16 hf[8]; } v0, v1;
  if (fits) {
    int j = lo;
    for (; j + 4 <= hi; j += 4) {
      int jj0 = j + eh, jj1 = j + 2 + eh;
      int s0 = esrc[jj0], s1 = esrc[jj1];
      float t0 = alf[wid][jj0 - lo][h];
      float t1 = alf[wid][jj1 - lo][h];
      v0.u = *(const uint4*)(xlh + (long)s0 * kC + c);
      v1.u = *(const uint4*)(xlh + (long)s1 * kC + c);
#pragma unroll
      for (int i = 0; i < 8; i++) acc[i] += t0 * (float)v0.hf[i];
#pragma unroll
      for (int i = 0; i < 8; i++) acc[i] += t1 * (float)v1.hf[i];
    }
    for (; j < hi; j += 2) {
      int jj = j + eh;
      bool valid = jj < hi;
      int js = valid ? jj : lo;
      int sn = esrc[js];
      float att = valid ? alf[wid][jj - lo][h] : 0.f;
      v0.u = *(const uint4*)(xlh + (long)sn * kC + c);
#pragma unroll
      for (int i = 0; i < 8; i++) acc[i] += att * (float)v0.hf[i];
    }
  } else {
    float adh = a_dst[n * kH + h];
    for (int j = lo; j < hi; j += 2) {
      int jj = j + eh;
      bool valid = jj < hi;
      int js = valid ? jj : lo;
      int sn = esrc[js];
      float a = a_src[sn * kH + h] + adh + aq[(long)js * kH + h];
      a = a > 0.f ? a : 0.2f * a;
      float att = valid ? __expf(a - mh) : 0.f;
      v0.u = *(const uint4*)(xlh + (long)sn * kC + c);
#pragma unroll
      for (int i = 0; i < 8; i++) acc[i] += att * (float)v0.hf[i];
    }
  }
#pragma unroll
  for (int i = 0; i < 8; i++) acc[i] += __shfl_xor(acc[i], 32);
  if (eh == 0) {
    float4 b0 = *(const float4*)(bias + c);
    float4 b1 = *(const float4*)(bias + c + 4);
    ushort o[8];
    o[0] = f2h(acc[0] * invs + b0.x); o[1] = f2h(acc[1] * invs + b0.y);
    o[2] = f2h(acc[2] * invs + b0.z); o[3] = f2h(acc[3] * invs + b0.w);
    o[4] = f2h(acc[4] * invs + b1.x); o[5] = f2h(acc[5] * invs + b1.y);
    o[6] = f2h(acc[6] * invs + b1.z); o[7] = f2h(acc[7] * invs + b1.w);
    *(uint4*)(hh + (long)n * kC + c) = *(uint4*)o;
  }
}

// ---------------- pooling (batch sorted -> segmented reduce) ----------------
__global__ __launch_bounds__(256) void gat_pool_seg(const ushort* __restrict__ h3h,
                                                    const int* __restrict__ batch,
                                                    ushort* __restrict__ hpoolh) {
  int m = blockIdx.x;
  int c = threadIdx.x;
  int lo = 0, hi = kN;
  while (lo < hi) { int mid = (lo + hi) >> 1; if (batch[mid] < m) lo = mid + 1; else hi = mid; }
  int start = lo;
  hi = kN;
  while (lo < hi) { int mid = (lo + hi) >> 1; if (batch[mid] < m + 1) lo = mid + 1; else hi = mid; }
  int end = lo;
  float s = 0.f;
  for (int n = start; n < end; n++) s += h2f(h3h[(long)n * kC + c]);
  hpoolh[(long)m * kC + c] = f2h(s);
}

__global__ void gat_mlp3(const float* __restrict__ c2, const float* __restrict__ lw3,
                         const float* __restrict__ lb3, float* __restrict__ out) {
  int n = blockIdx.x * blockDim.x + threadIdx.x;
  if (n >= kN) return;
  float s = lb3[0];
  const float* r = c2 + (long)n * 64;
#pragma unroll
  for (int k = 0; k < 64; k++) s += r[k] * lw3[k];
  float v = 1.f / (1.f + __expf(-s));
  out[n] = v;
}

// ---------------- host ----------------
static inline int cdiv(int a, int b) { return (a + b - 1) / b; }

extern "C" void kernel_launch(void* const* d_in, const int* in_sizes, int n_in,
                              void* d_out, int out_size, void* d_ws, size_t ws_size,
                              hipStream_t stream) {
  (void)in_sizes; (void)n_in; (void)out_size; (void)ws_size;
  const float* x = (const float*)d_in[0];
  const int* ei = (const int*)d_in[1];
  const float* ea = (const float*)d_in[2];
  const int* batch = (const int*)d_in[3];
  const float *W[3], *as_[3], *ad_[3], *We_[3], *ae_[3], *bb[3];
  for (int l = 0; l < 3; l++) {
    W[l]   = (const float*)d_in[4 + 6 * l];
    as_[l] = (const float*)d_in[5 + 6 * l];
    ad_[l] = (const float*)d_in[6 + 6 * l];
    We_[l] = (const float*)d_in[7 + 6 * l];
    ae_[l] = (const float*)d_in[8 + 6 * l];
    bb[l]  = (const float*)d_in[9 + 6 * l];
  }
  const float* lw1 = (const float*)d_in[22];
  const float* lb1 = (const float*)d_in[23];
  const float* lw2 = (const float*)d_in[24];
  const float* lb2 = (const float*)d_in[25];
  const float* lw3 = (const float*)d_in[26];
  const float* lb3 = (const float*)d_in[27];
  float* out = (float*)d_out;

  char* p = (char*)d_ws;
  auto carve = [&](size_t bytes) -> void* {
    void* r = (void*)p;
    p += (bytes + 255) & ~(size_t)255;
    return r;
  };
  float* aq0     = (float*)carve(sizeof(float) * (size_t)kEtot * kH);
  float* aq1     = (float*)carve(sizeof(float) * (size_t)kEtot * kH);
  float* aq2     = (float*)carve(sizeof(float) * (size_t)kEtot * kH);
  float* a_src   = (float*)carve(sizeof(float) * (size_t)kN * kH);
  float* a_dst   = (float*)carve(sizeof(float) * (size_t)kN * kH);
  float* Q3      = (float*)carve(sizeof(float) * 3 * 128);
  float* c2      = (float*)carve(sizeof(float) * (size_t)kN * 64);
  ushort* xh     = (ushort*)carve(sizeof(ushort) * (size_t)kN * 64);
  ushort* xlh    = (ushort*)carve(sizeof(ushort) * (size_t)kN * kC);
  ushort* h1h    = (ushort*)carve(sizeof(ushort) * (size_t)kN * kC);
  ushort* h2h    = (ushort*)carve(sizeof(ushort) * (size_t)kN * kC);
  ushort* h3h    = (ushort*)carve(sizeof(ushort) * (size_t)kN * kC);
  ushort* hpoolh = (ushort*)carve(sizeof(ushort) * (size_t)kNM * kC);
  ushort* Wt1    = (ushort*)carve(sizeof(ushort) * 64 * 256);
  ushort* Wt2    = (ushort*)carve(sizeof(ushort) * 256 * 256);
  ushort* Wt3    = (ushort*)carve(sizeof(ushort) * 256 * 256);
  ushort* lwt1   = (ushort*)carve(sizeof(ushort) * 1024 * 96);
  ushort* lwt2p  = (ushort*)carve(sizeof(ushort) * 64 * 128);
  int* deg   = (int*)carve(sizeof(int) * kN);
  int* fillc = (int*)carve(sizeof(int) * kN);
  int* offs  = (int*)carve(sizeof(int) * (kN + 1));
  int* bsum  = (int*)carve(sizeof(int) * 256);
  int* bpre  = (int*)carve(sizeof(int) * 256);
  int* el    = (int*)carve(sizeof(int) * kEtot);
  int* esrc  = (int*)carve(sizeof(int) * kEtot);
  int* epos  = (int*)carve(sizeof(int) * kEtot);
  // dead-buffer alias: MLP1 intermediate (aq planes dead after layer-3 aggregate)
  ushort* c1h = (ushort*)aq0;  // kN*128 ushorts (12.8MB) <= 27.2MB

  // ---- zero counters + conversions + Q ----
  gat_zero2<<<cdiv(kN, 256), 256, 0, stream>>>(deg, fillc, kN);
  {
    int tot = kN * 64 + 256 * 64 + 2 * 256 * 256 + 96 * 1024 + 64 * 128;
    cvt_all<<<cdiv(tot, 256), 256, 0, stream>>>(x, W[0], W[1], W[2], lw1, lw2,
                                                xh, Wt1, Wt2, Wt3, lwt1, lwt2p);
  }
  gat_make_q3<<<1, 384, 0, stream>>>(We_[0], ae_[0], We_[1], ae_[1], We_[2], ae_[2], Q3);

  // ---- CSR build + edge-coefficient precompute (all 3 layers at once) ----
  gat_count<<<cdiv(kE, 256), 256, 0, stream>>>(ei, deg);
  gat_scan_a<<<kNB, 256, 0, stream>>>(deg, offs, bsum);
  gat_scan_b<<<1, 256, 0, stream>>>(bsum, bpre);
  gat_scan_c<<<kNB, 256, 0, stream>>>(offs, bpre);
  gat_fill<<<cdiv(kEtot, 256), 256, 0, stream>>>(ei, offs, fillc, el, esrc, epos);
  gat_aq<<<cdiv(kEtot, 256), 256, 0, stream>>>(el, ea, Q3, aq0, aq1, aq2);
  gat_aqsum<<<cdiv(kN * kH, 256), 256, 0, stream>>>(offs, epos, aq0, aq1, aq2);

  // ---- 3 GAT layers ----
  const ushort* hinh[3] = {xh, h1h, h2h};
  ushort* houth[3] = {h1h, h2h, h3h};
  const ushort* Wt[3] = {Wt1, Wt2, Wt3};
  const float* aqP[3] = {aq0, aq1, aq2};
  int kdim[3] = {64, kC, kC};
  for (int l = 0; l < 3; l++) {
    dim3 ggrid(kC / 128, cdiv(kN, 64));
    gat_gemm_mfma<0, 1><<<ggrid, 256, 0, stream>>>(
        kN, kdim[l], kC, hinh[l], nullptr, nullptr, nullptr, nullptr,
        Wt[l], nullptr, nullptr, 0, xlh, kC, 0,
        as_[l], ad_[l], a_src, a_dst);
    gat_aggregate<<<kN / 4, 256, 0, stream>>>(offs, esrc, aqP[l], a_src, a_dst,
                                              xlh, bb[l], houth[l]);
  }

  // ---- pooling (segmented, batch sorted) ----
  gat_pool_seg<<<kNM, kC, 0, stream>>>(h3h, batch, hpoolh);

  // ---- MLP ----
  {
    gat_zeropad<<<cdiv(kN * 4, 256), 256, 0, stream>>>(c1h);
    dim3 g1(1, cdiv(kN, 64));
    gat_gemm_mfma<2, 0><<<g1, 256, 0, stream>>>(
        kN, 4 * kC, 96, h1h, h2h, h3h, hpoolh, batch,
        lwt1, lb1, nullptr, 0, c1h, 128, 1,
        nullptr, nullptr, nullptr, nullptr);
    dim3 g2(1, cdiv(kN, 64));
    gat_gemm_mfma<0, 0><<<g2, 256, 0, stream>>>(
        kN, 128, 64, c1h, nullptr, nullptr, nullptr, nullptr,
        lwt2p, lb2, c2, 64, nullptr, 0, 1,
        nullptr, nullptr, nullptr, nullptr);
    gat_mlp3<<<cdiv(kN, 256), 256, 0, stream>>>(c2, lw3, lb3, out);
  }
}